// Round 3
// baseline (630.471 us; speedup 1.0000x reference)
//
#include <hip/hip_runtime.h>
#include <hip/hip_fp16.h>
#include <math.h>

// Problem constants (match reference)
#define R_TOT 4096
#define L_LEN 128
#define D_DIM 200
#define A_DIM 20
#define NEGK  2
#define B_SZ  1024
#define NNZ_C 20480
#define RN_TOT (R_TOT*NEGK)
#define S_TOT (R_TOT + RN_TOT)
#define VOCAB_C 32000
#define EPS_ 1e-12f
#define SLOT_CAP 64          // Poisson(20) max bin ~45; 64 is safe
#define NBUCK_BLK 160        // 160*256 = 40960 = 2*NNZ_C
#define NREV 4               // reviews per k_attn block (pipelined)

__device__ __forceinline__ float4 unpack4(const uint2 u) {
  union { unsigned v; __half2 h; } c0, c1;
  c0.v = u.x; c1.v = u.y;
  const float2 f0 = __half22float2(c0.h);
  const float2 f1 = __half22float2(c1.h);
  return make_float4(f0.x, f0.y, f1.x, f1.y);
}

// ---------------- K0: cast emb -> fp16 table; block 0 also zeroes bucket counters ----------------
__global__ __launch_bounds__(256) void k_cast(
    const float* __restrict__ emb, ushort* __restrict__ emb_h, int* __restrict__ cnt)
{
  if (blockIdx.x == 0) {
    for (int i = threadIdx.x; i < 2*B_SZ; i += 256) cnt[i] = 0;
  }
  const int idx = blockIdx.x*256 + threadIdx.x;
  if (idx < (VOCAB_C*D_DIM)/4) {
    const float4 v = reinterpret_cast<const float4*>(emb)[idx];
    ushort4 o;
    o.x = __half_as_ushort(__float2half(v.x));
    o.y = __half_as_ushort(__float2half(v.y));
    o.z = __half_as_ushort(__float2half(v.z));
    o.w = __half_as_ushort(__float2half(v.w));
    reinterpret_cast<ushort4*>(emb_h)[idx] = o;
  }
}

// ---------------- K1: combined means (pos+neg) + bucket tail ----------------
__global__ __launch_bounds__(256, 8) void k_means2(
    const int* __restrict__ hist, const int* __restrict__ neg,
    const ushort* __restrict__ emb_h,
    float* __restrict__ ys_all, float* __restrict__ zn_all,
    const int* __restrict__ uidx, const float* __restrict__ uval,
    const int* __restrict__ iidx, const float* __restrict__ ival,
    int* __restrict__ cnt, int* __restrict__ scol, float* __restrict__ sval)
{
  const int sb = blockIdx.x;
  const int tid = threadIdx.x;

  if (sb >= S_TOT) {
    const int g = (sb - S_TOT)*256 + tid;
    if (g < NNZ_C) {
      const int b = uidx[g];
      const int slot = atomicAdd(&cnt[b], 1);
      if (slot < SLOT_CAP) {
        scol[b*SLOT_CAP + slot] = uidx[NNZ_C + g];
        sval[b*SLOT_CAP + slot] = uval[g];
      }
    } else {
      const int g2 = g - NNZ_C;
      const int b = iidx[g2];
      const int slot = atomicAdd(&cnt[B_SZ + b], 1);
      if (slot < SLOT_CAP) {
        scol[(B_SZ + b)*SLOT_CAP + slot] = iidx[NNZ_C + g2];
        sval[(B_SZ + b)*SLOT_CAP + slot] = ival[g2];
      }
    }
    return;
  }

  __shared__ int widx[L_LEN];
  __shared__ __align__(16) float part[8][D_DIM];
  const bool is_pos = (sb < R_TOT);
  const int* src = is_pos ? (hist + (size_t)sb*L_LEN)
                          : (neg + (size_t)(sb - R_TOT)*L_LEN);
  if (tid < L_LEN) widx[tid] = src[tid];
  __syncthreads();

  const int c5 = tid & 31;       // column chunk (active if < 25)
  const int j  = tid >> 5;       // 0..7 row group
  float4 sA = {0.f,0.f,0.f,0.f}, sB = {0.f,0.f,0.f,0.f};
  if (c5 < 25) {
    const size_t coff = 8*c5;
    #pragma unroll
    for (int k0 = 0; k0 < 16; k0 += 4) {
      const uint4 q0 = *reinterpret_cast<const uint4*>(
          emb_h + (size_t)widx[j + 8*(k0+0)]*D_DIM + coff);
      const uint4 q1 = *reinterpret_cast<const uint4*>(
          emb_h + (size_t)widx[j + 8*(k0+1)]*D_DIM + coff);
      const uint4 q2 = *reinterpret_cast<const uint4*>(
          emb_h + (size_t)widx[j + 8*(k0+2)]*D_DIM + coff);
      const uint4 q3 = *reinterpret_cast<const uint4*>(
          emb_h + (size_t)widx[j + 8*(k0+3)]*D_DIM + coff);
      float4 e;
      e = unpack4(make_uint2(q0.x,q0.y)); sA.x+=e.x; sA.y+=e.y; sA.z+=e.z; sA.w+=e.w;
      e = unpack4(make_uint2(q0.z,q0.w)); sB.x+=e.x; sB.y+=e.y; sB.z+=e.z; sB.w+=e.w;
      e = unpack4(make_uint2(q1.x,q1.y)); sA.x+=e.x; sA.y+=e.y; sA.z+=e.z; sA.w+=e.w;
      e = unpack4(make_uint2(q1.z,q1.w)); sB.x+=e.x; sB.y+=e.y; sB.z+=e.z; sB.w+=e.w;
      e = unpack4(make_uint2(q2.x,q2.y)); sA.x+=e.x; sA.y+=e.y; sA.z+=e.z; sA.w+=e.w;
      e = unpack4(make_uint2(q2.z,q2.w)); sB.x+=e.x; sB.y+=e.y; sB.z+=e.z; sB.w+=e.w;
      e = unpack4(make_uint2(q3.x,q3.y)); sA.x+=e.x; sA.y+=e.y; sA.z+=e.z; sA.w+=e.w;
      e = unpack4(make_uint2(q3.z,q3.w)); sB.x+=e.x; sB.y+=e.y; sB.z+=e.z; sB.w+=e.w;
    }
    *reinterpret_cast<float4*>(&part[j][8*c5])     = sA;
    *reinterpret_cast<float4*>(&part[j][8*c5 + 4]) = sB;
  }
  __syncthreads();
  float* dst = is_pos ? (ys_all + (size_t)sb*D_DIM)
                      : (zn_all + (size_t)(sb - R_TOT)*D_DIM);
  if (tid < D_DIM) {
    float a = 0.f;
    #pragma unroll
    for (int j2 = 0; j2 < 8; ++j2) a += part[j2][tid];
    dst[tid] = a * (1.0f/128.0f);
  }
}

// ---------------- K2: V = Y @ Wm (16 reviews/block) ----------------
#define KB_RT 16
__global__ __launch_bounds__(256, 2) void k_matvec(
    const float* __restrict__ ys_all, const float* __restrict__ Wm,
    float* __restrict__ vv_all)
{
  __shared__ float ysl[KB_RT][D_DIM];
  const int r0 = blockIdx.x * KB_RT;
  const int tid = threadIdx.x;
  for (int i = tid; i < KB_RT*D_DIM; i += 256)
    ysl[i / D_DIM][i % D_DIM] = ys_all[(size_t)r0*D_DIM + i];
  __syncthreads();
  if (tid < D_DIM) {
    float acc[KB_RT];
    #pragma unroll
    for (int r = 0; r < KB_RT; ++r) acc[r] = 0.f;
    #pragma unroll 4
    for (int k = 0; k < D_DIM; ++k) {
      const float w = Wm[k*D_DIM + tid];
      #pragma unroll
      for (int r = 0; r < KB_RT; ++r) acc[r] += ysl[r][k] * w;
    }
    #pragma unroll
    for (int r = 0; r < KB_RT; ++r)
      vv_all[(size_t)(r0 + r)*D_DIM + tid] = acc[r];
  }
}

// ---------------- K3: pipelined attn — NREV reviews/block, register prefetch of next tile ----------------
// Per review: ONE gather pass (dx computed during LDS staging from prefetched regs),
// z_s from LDS. While review i runs softmax/z_s/p_t/r_s (serial, barrier-heavy),
// review i+1's widx + 8 uint4 gathers + vv are already in flight into REGISTERS
// (T14 issue-early/consume-late). zn rows for the epilogue prefetched before softmax.
// LDS 53.4 KB -> 3 blocks/CU.
__global__ __launch_bounds__(512, 6) void k_attn(
    const int* __restrict__ hist, const ushort* __restrict__ emb_h,
    const float* __restrict__ vv_all,
    const float* __restrict__ Ww, const float* __restrict__ bw,
    const float* __restrict__ Wt, const float* __restrict__ zn_all,
    float* __restrict__ rs_out, float* __restrict__ abae)
{
  __shared__ __align__(16) ushort ew[L_LEN*D_DIM];   // 51200 B, (L,D) row-major fp16
  __shared__ __align__(16) float ax[L_LEN];          // 512 B
  __shared__ __align__(16) float zs[D_DIM];          // 800 B
  __shared__ __align__(16) float ubuf[240];          // 960 B: ptile [0..160), red [160..240)
  float* ptile = ubuf;
  float* red   = ubuf + 160;

  const int tid = threadIdx.x, lane = tid & 63, wv = tid >> 6;
  const int c5 = tid & 31;      // column chunk (active if < 25)
  const int j  = tid >> 5;      // 0..15 row group
  const bool act = (c5 < 25);
  const int coff = 8*c5;
  const int r0 = blockIdx.x * NREV;

  // ---- prologue: widx + tile gathers + vv for review r0 ----
  uint4 q0,q1,q2,q3,q4,q5,q6,q7;
  q0=q1=q2=q3=q4=q5=q6=q7=make_uint4(0,0,0,0);
  float4 v8a = {0,0,0,0}, v8b = {0,0,0,0};
  if (act) {
    const int base = r0*L_LEN + j;
    const int w0 = hist[base],     w1 = hist[base+16], w2 = hist[base+32], w3 = hist[base+48];
    const int w4 = hist[base+64],  w5 = hist[base+80], w6 = hist[base+96], w7 = hist[base+112];
    q0 = *reinterpret_cast<const uint4*>(emb_h + (size_t)w0*D_DIM + coff);
    q1 = *reinterpret_cast<const uint4*>(emb_h + (size_t)w1*D_DIM + coff);
    q2 = *reinterpret_cast<const uint4*>(emb_h + (size_t)w2*D_DIM + coff);
    q3 = *reinterpret_cast<const uint4*>(emb_h + (size_t)w3*D_DIM + coff);
    q4 = *reinterpret_cast<const uint4*>(emb_h + (size_t)w4*D_DIM + coff);
    q5 = *reinterpret_cast<const uint4*>(emb_h + (size_t)w5*D_DIM + coff);
    q6 = *reinterpret_cast<const uint4*>(emb_h + (size_t)w6*D_DIM + coff);
    q7 = *reinterpret_cast<const uint4*>(emb_h + (size_t)w7*D_DIM + coff);
    v8a = *reinterpret_cast<const float4*>(vv_all + (size_t)r0*D_DIM + coff);
    v8b = *reinterpret_cast<const float4*>(vv_all + (size_t)r0*D_DIM + coff + 4);
  }

  for (int i = 0; i < NREV; ++i) {
    const int r = r0 + i;

    // issue next review's widx loads early (registers only, no LDS hazard)
    int w0n=0,w1n=0,w2n=0,w3n=0,w4n=0,w5n=0,w6n=0,w7n=0;
    if (act && i < NREV-1) {
      const int nb = (r+1)*L_LEN + j;
      w0n = hist[nb];     w1n = hist[nb+16]; w2n = hist[nb+32]; w3n = hist[nb+48];
      w4n = hist[nb+64];  w5n = hist[nb+80]; w6n = hist[nb+96]; w7n = hist[nb+112];
    }

    __syncthreads();   // previous iteration's ew readers are done

    // ---- stage tile from regs to LDS + dx partials ----
    float p0=0.f,p1=0.f,p2=0.f,p3=0.f,p4=0.f,p5=0.f,p6=0.f,p7=0.f;
    if (act) {
      #define STG(K, Q, P) { \
        *reinterpret_cast<uint4*>(ew + (j + 16*(K))*D_DIM + coff) = Q; \
        const float4 e0_ = unpack4(make_uint2(Q.x, Q.y)); \
        const float4 e1_ = unpack4(make_uint2(Q.z, Q.w)); \
        P = e0_.x*v8a.x + e0_.y*v8a.y + e0_.z*v8a.z + e0_.w*v8a.w \
          + e1_.x*v8b.x + e1_.y*v8b.y + e1_.z*v8b.z + e1_.w*v8b.w; }
      STG(0,q0,p0) STG(1,q1,p1) STG(2,q2,p2) STG(3,q3,p3)
      STG(4,q4,p4) STG(5,q5,p5) STG(6,q6,p6) STG(7,q7,p7)
      #undef STG
      // refill prefetch regs for review r+1 (in flight through softmax/z_s/epilogue)
      if (i < NREV-1) {
        q0 = *reinterpret_cast<const uint4*>(emb_h + (size_t)w0n*D_DIM + coff);
        q1 = *reinterpret_cast<const uint4*>(emb_h + (size_t)w1n*D_DIM + coff);
        q2 = *reinterpret_cast<const uint4*>(emb_h + (size_t)w2n*D_DIM + coff);
        q3 = *reinterpret_cast<const uint4*>(emb_h + (size_t)w3n*D_DIM + coff);
        q4 = *reinterpret_cast<const uint4*>(emb_h + (size_t)w4n*D_DIM + coff);
        q5 = *reinterpret_cast<const uint4*>(emb_h + (size_t)w5n*D_DIM + coff);
        q6 = *reinterpret_cast<const uint4*>(emb_h + (size_t)w6n*D_DIM + coff);
        q7 = *reinterpret_cast<const uint4*>(emb_h + (size_t)w7n*D_DIM + coff);
      }
    }
    // prefetch next vv + current zn rows (used after z_s)
    float4 v8an = {0,0,0,0}, v8bn = {0,0,0,0};
    if (act && i < NREV-1) {
      v8an = *reinterpret_cast<const float4*>(vv_all + (size_t)(r+1)*D_DIM + coff);
      v8bn = *reinterpret_cast<const float4*>(vv_all + (size_t)(r+1)*D_DIM + coff + 4);
    }
    float zn0 = 0.f, zn1 = 0.f;
    if (tid < D_DIM) {
      zn0 = zn_all[(size_t)(2*r)*D_DIM + tid];
      zn1 = zn_all[(size_t)(2*r + 1)*D_DIM + tid];
    }

    // dx reduce over the 25 active c5 lanes of each half-wave (inactive lanes hold 0)
    #pragma unroll
    for (int o = 16; o > 0; o >>= 1) {
      p0 += __shfl_xor(p0, o); p1 += __shfl_xor(p1, o);
      p2 += __shfl_xor(p2, o); p3 += __shfl_xor(p3, o);
      p4 += __shfl_xor(p4, o); p5 += __shfl_xor(p5, o);
      p6 += __shfl_xor(p6, o); p7 += __shfl_xor(p7, o);
    }
    if (c5 == 0) {
      ax[j]      = p0; ax[j + 16]  = p1; ax[j + 32]  = p2; ax[j + 48]  = p3;
      ax[j + 64] = p4; ax[j + 80]  = p5; ax[j + 96]  = p6; ax[j + 112] = p7;
    }
    __syncthreads();

    // ---- softmax over 128 (wave 0 reduces) ----
    if (tid < 64) {
      float m = fmaxf(ax[tid], ax[tid+64]);
      #pragma unroll
      for (int o = 32; o > 0; o >>= 1) m = fmaxf(m, __shfl_xor(m, o));
      if (tid == 0) red[0] = m;
    }
    __syncthreads();
    const float M = red[0];
    if (tid < L_LEN) ax[tid] = expf(ax[tid] - M);
    __syncthreads();
    if (tid < 64) {
      float s = ax[tid] + ax[tid+64];
      #pragma unroll
      for (int o = 32; o > 0; o >>= 1) s += __shfl_xor(s, o);
      if (tid == 0) red[1] = s;
    }
    __syncthreads();
    const float Sinv = 1.0f / red[1];
    if (tid < L_LEN) ax[tid] *= Sinv;
    __syncthreads();

    // ---- z_s from LDS, flat (reshape) indexing; quarter-wave per d-window ----
    {
      const int lq = lane & 15;
      const int quad = lane >> 4;
      const float4 ax8a = *reinterpret_cast<const float4*>(ax + 8*lq);
      const float4 ax8b = *reinterpret_cast<const float4*>(ax + 8*lq + 4);
      for (int dq = wv; dq < 50; dq += 8) {
        const int d0 = 4*dq + quad;
        const int f0 = (d0 << 7) + 8*lq;      // flat half-index, 16B aligned
        const uint4 q = *reinterpret_cast<const uint4*>(ew + f0);
        const float4 e0 = unpack4(make_uint2(q.x, q.y));
        const float4 e1 = unpack4(make_uint2(q.z, q.w));
        float a = e0.x*ax8a.x + e0.y*ax8a.y + e0.z*ax8a.z + e0.w*ax8a.w
                + e1.x*ax8b.x + e1.y*ax8b.y + e1.z*ax8b.z + e1.w*ax8b.w;
        #pragma unroll
        for (int o = 8; o > 0; o >>= 1) a += __shfl_xor(a, o);
        if (lq == 0) zs[d0] = a;
      }
    }
    __syncthreads();

    // ---- p_t[a] = z_s . Ww[a,:] + bw[a] — 8x20 partials ----
    if (tid < 160) {
      const int a = tid % 20, jj = tid / 20;
      float s = 0.f;
      #pragma unroll
      for (int ii = 0; ii < 25; ++ii) {
        const int d = jj + 8*ii;
        s += zs[d] * Ww[a*D_DIM + d];
      }
      ptile[tid] = s;
    }
    __syncthreads();
    if (tid < A_DIM) {
      float s = bw[tid];
      #pragma unroll
      for (int jj = 0; jj < 8; ++jj) s += ptile[jj*20 + tid];
      red[2 + tid] = s;
    }
    __syncthreads();

    // ---- r_s + fused norms for c1 and both c2 rows ----
    float rsd = 0.f, zsd = 0.f;
    if (tid < D_DIM) {
      float acc = 0.f;
      #pragma unroll
      for (int a = 0; a < A_DIM; ++a) acc += red[2+a] * Wt[tid*A_DIM + a];
      rsd = acc; zsd = zs[tid];
      rs_out[(size_t)r*D_DIM + tid] = acc;
    } else { zn0 = 0.f; zn1 = 0.f; }
    float a0 = rsd*rsd, a1 = zsd*zsd, a2 = rsd*zsd;
    float b0 = zn0*zn0, b1 = zn0*rsd, b2 = zn1*zn1, b3 = zn1*rsd;
    #pragma unroll
    for (int o = 32; o > 0; o >>= 1) {
      a0 += __shfl_xor(a0, o); a1 += __shfl_xor(a1, o); a2 += __shfl_xor(a2, o);
      b0 += __shfl_xor(b0, o); b1 += __shfl_xor(b1, o);
      b2 += __shfl_xor(b2, o); b3 += __shfl_xor(b3, o);
    }
    if ((tid & 63) == 0) {
      red[22+wv] = a0; red[30+wv] = a1; red[38+wv] = a2;
      red[46+wv] = b0; red[54+wv] = b1; red[62+wv] = b2; red[70+wv] = b3;
    }
    __syncthreads();
    if (tid == 0) {
      float s0=0.f,s1=0.f,s2=0.f,t0=0.f,t1=0.f,t2=0.f,t3=0.f;
      #pragma unroll
      for (int ii = 0; ii < 8; ++ii) {
        s0 += red[22+ii]; s1 += red[30+ii]; s2 += red[38+ii];
        t0 += red[46+ii]; t1 += red[54+ii]; t2 += red[62+ii]; t3 += red[70+ii];
      }
      const float nr = fmaxf(sqrtf(s0), EPS_);
      const float nz = fmaxf(sqrtf(s1), EPS_);
      const float c1 = s2 / (nr * nz);
      const float c2a = t1 / (fmaxf(sqrtf(t0), EPS_) * nr);
      const float c2b = t3 / (fmaxf(sqrtf(t2), EPS_) * nr);
      abae[2*r]     = fmaxf(c2a - c1 + 1.0f, 0.0f);
      abae[2*r + 1] = fmaxf(c2b - c1 + 1.0f, 0.0f);
    }

    // rotate vv prefetch
    v8a = v8an; v8b = v8bn;
  }
}

// ---------------- K4: merged segment-sum apply + FM (one block per b) ----------------
__global__ __launch_bounds__(512) void k_aggfm(
    const int* __restrict__ cnt, const int* __restrict__ scol,
    const float* __restrict__ sval, const float* __restrict__ rs,
    const float* __restrict__ fcw, const float* __restrict__ V,
    float* __restrict__ uae, float* __restrict__ iae,
    float* __restrict__ linb, float* __restrict__ quadb)
{
  __shared__ __align__(16) float ivec[2*D_DIM];
  __shared__ float redw[8];
  __shared__ float qpart[10];
  const int b = blockIdx.x;
  const int tid = threadIdx.x, lane = tid & 63, wv = tid >> 6;

  if (tid < D_DIM) {
    int n = cnt[b]; n = n < SLOT_CAP ? n : SLOT_CAP;
    const int* cols = scol + (size_t)b*SLOT_CAP;
    const float* vals = sval + (size_t)b*SLOT_CAP;
    float acc = 0.f;
    for (int j = 0; j < n; ++j) acc += vals[j] * rs[(size_t)cols[j]*D_DIM + tid];
    ivec[tid] = acc;
    uae[(size_t)b*D_DIM + tid] = acc;
  } else if (tid >= 256 && tid < 256 + D_DIM) {
    const int t = tid - 256;
    int n = cnt[B_SZ + b]; n = n < SLOT_CAP ? n : SLOT_CAP;
    const int* cols = scol + (size_t)(B_SZ + b)*SLOT_CAP;
    const float* vals = sval + (size_t)(B_SZ + b)*SLOT_CAP;
    float acc = 0.f;
    for (int j = 0; j < n; ++j) acc += vals[j] * rs[(size_t)cols[j]*D_DIM + t];
    ivec[D_DIM + t] = acc;
    iae[(size_t)b*D_DIM + t] = acc;
  }
  __syncthreads();

  float lv = 0.f;
  if (tid < 2*D_DIM) lv = ivec[tid] * fcw[tid];
  #pragma unroll
  for (int o = 32; o > 0; o >>= 1) lv += __shfl_xor(lv, o);
  if (lane == 0) redw[wv] = lv;

  {
    const int k = wv;
    float s1 = 0.f, s2 = 0.f;
    for (int f = lane; f < 2*D_DIM; f += 64) {
      const float x = ivec[f];
      const float vk = V[f*10 + k];
      s1 += x*vk; s2 += x*x*vk*vk;
    }
    #pragma unroll
    for (int o = 32; o > 0; o >>= 1) { s1 += __shfl_xor(s1,o); s2 += __shfl_xor(s2,o); }
    if (lane == 0) qpart[k] = s1*s1 - s2;
  }
  if (wv < 2) {
    const int k = 8 + wv;
    float s1 = 0.f, s2 = 0.f;
    for (int f = lane; f < 2*D_DIM; f += 64) {
      const float x = ivec[f];
      const float vk = V[f*10 + k];
      s1 += x*vk; s2 += x*x*vk*vk;
    }
    #pragma unroll
    for (int o = 32; o > 0; o >>= 1) { s1 += __shfl_xor(s1,o); s2 += __shfl_xor(s2,o); }
    if (lane == 0) qpart[k] = s1*s1 - s2;
  }
  __syncthreads();
  if (tid == 0) {
    float lin = 0.f;
    #pragma unroll
    for (int i = 0; i < 8; ++i) lin += redw[i];
    float q = 0.f;
    #pragma unroll
    for (int i = 0; i < 10; ++i) q += qpart[i];
    linb[b] = lin; quadb[b] = q;
  }
}

// ---------------- K5: fused quad-reduce + prediction + all final scalars ----------------
__global__ __launch_bounds__(1024) void k_final2(
    const float* __restrict__ quadb, const float* __restrict__ linb,
    const float* __restrict__ fcb, const int* __restrict__ user,
    const int* __restrict__ item, const float* __restrict__ busers,
    const float* __restrict__ bitems, const float* __restrict__ label,
    const float* __restrict__ Wt, const float* __restrict__ abae,
    float* __restrict__ pred, float* __restrict__ rl, float* __restrict__ obj)
{
  __shared__ float sA[16], sB[16], sC[16];
  __shared__ float cninv[A_DIM];
  __shared__ float quad_s;
  const int tid = threadIdx.x;
  const int lane = tid & 63;
  const int wv = tid >> 6;

  float q = quadb[tid];
  #pragma unroll
  for (int o = 32; o > 0; o >>= 1) q += __shfl_xor(q, o);
  if (lane == 0) sA[wv] = q;

  if (tid < A_DIM) {
    float s = 0.f;
    for (int d = 0; d < D_DIM; ++d) { const float w = Wt[d*A_DIM + tid]; s += w*w; }
    cninv[tid] = 1.0f / fmaxf(sqrtf(s), EPS_);
  }
  __syncthreads();
  if (wv == 0) {
    float s = (lane < 16) ? sA[lane] : 0.f;
    #pragma unroll
    for (int o = 32; o > 0; o >>= 1) s += __shfl_xor(s, o);
    if (lane == 0) quad_s = s;
  }
  __syncthreads();

  const float p = 0.5f*quad_s + linb[tid] + fcb[0]
                + busers[user[tid]] + bitems[item[tid]];
  pred[tid] = p;
  const float dd = p - label[tid];
  const float myrl = dd*dd;
  rl[tid] = myrl;

  float u = 0.f;
  if (tid < 400) {
    const int a = tid / 20, c = tid % 20;
    float dot = 0.f;
    for (int d = 0; d < D_DIM; ++d) dot += Wt[d*A_DIM + a]*Wt[d*A_DIM + c];
    const float g = dot*cninv[a]*cninv[c] - (a==c ? 1.0f : 0.0f);
    u = g*g;
  }
  float js = 0.f;
  #pragma unroll
  for (int j = 0; j < 8; ++j) js += abae[tid + 1024*j];
  float ms = myrl;

  #pragma unroll
  for (int o = 32; o > 0; o >>= 1) {
    u += __shfl_xor(u,o); js += __shfl_xor(js,o); ms += __shfl_xor(ms,o);
  }
  if (lane == 0) { sA[wv] = u; sB[wv] = js; sC[wv] = ms; }
  __syncthreads();
  if (tid == 0) {
    float U = 0.f, J = 0.f, Ms = 0.f;
    for (int i = 0; i < 16; ++i) { U += sA[i]; J += sB[i]; Ms += sC[i]; }
    obj[0] = Ms/1024.0f + 0.01f*(J/8192.0f) + 0.01f*(U/400.0f);
  }
}

extern "C" void kernel_launch(void* const* d_in, const int* in_sizes, int n_in,
                              void* d_out, int out_size, void* d_ws, size_t ws_size,
                              hipStream_t stream) {
  const int*   hist   = (const int*)  d_in[0];
  const int*   neg    = (const int*)  d_in[1];
  const int*   user   = (const int*)  d_in[2];
  const int*   item   = (const int*)  d_in[3];
  const float* label  = (const float*)d_in[4];
  const int*   uidx   = (const int*)  d_in[5];
  const float* uval   = (const float*)d_in[6];
  const int*   iidx   = (const int*)  d_in[7];
  const float* ival   = (const float*)d_in[8];
  const float* emb    = (const float*)d_in[9];
  const float* Wm     = (const float*)d_in[10];
  const float* Ww     = (const float*)d_in[11];
  const float* bw     = (const float*)d_in[12];
  const float* Wt     = (const float*)d_in[13];
  const float* fcw    = (const float*)d_in[14];
  const float* fcb    = (const float*)d_in[15];
  const float* V      = (const float*)d_in[16];
  const float* busers = (const float*)d_in[17];
  const float* bitems = (const float*)d_in[18];

  float* out  = (float*)d_out;
  float* obj  = out;                       // 1
  float* rl   = out + 1;                   // 1024
  float* abae = out + 1 + B_SZ;            // 8192
  float* pred = out + 1 + B_SZ + RN_TOT;   // 1024
  float* uae  = pred + B_SZ;               // 204800
  float* iae  = uae + (size_t)B_SZ*D_DIM;  // 204800

  float* ws     = (float*)d_ws;
  float* rs     = ws;                              // R*D
  float* ys_all = rs + (size_t)R_TOT*D_DIM;        // R*D
  float* zn_all = ys_all + (size_t)R_TOT*D_DIM;    // RN*D
  float* vv_all = zn_all + (size_t)RN_TOT*D_DIM;   // R*D
  float* linb   = vv_all + (size_t)R_TOT*D_DIM;    // B
  float* quadb  = linb + B_SZ;                     // B
  float* sval   = quadb + B_SZ;                    // 2*B*SLOT_CAP floats
  int*   scol   = (int*)(sval + (size_t)2*B_SZ*SLOT_CAP);   // 2*B*SLOT_CAP ints
  int*   cnt    = scol + (size_t)2*B_SZ*SLOT_CAP;           // 2*B ints
  ushort* emb_h = (ushort*)(cnt + 2*B_SZ);                  // VOCAB*D halves

  const int cast_blocks = (VOCAB_C*D_DIM/4 + 255)/256;      // 6250

  k_cast  <<<cast_blocks, 256, 0, stream>>>(emb, emb_h, cnt);
  k_means2<<<S_TOT + NBUCK_BLK, 256, 0, stream>>>(hist, neg, emb_h,
                                                  ys_all, zn_all,
                                                  uidx, uval, iidx, ival,
                                                  cnt, scol, sval);
  k_matvec<<<R_TOT/KB_RT, 256, 0, stream>>>(ys_all, Wm, vv_all);
  k_attn  <<<R_TOT/NREV, 512, 0, stream>>>(hist, emb_h, vv_all, Ww, bw, Wt,
                                           zn_all, rs, abae);
  k_aggfm <<<B_SZ, 512, 0, stream>>>(cnt, scol, sval, rs, fcw, V,
                                     uae, iae, linb, quadb);
  k_final2<<<1, 1024, 0, stream>>>(quadb, linb, fcb, user, item, busers, bitems,
                                   label, Wt, abae, pred, rl, obj);
}

// Round 4
// 327.502 us; speedup vs baseline: 1.9251x; 1.9251x over previous
//
#include <hip/hip_runtime.h>
#include <hip/hip_fp16.h>
#include <math.h>

// Problem constants (match reference)
#define R_TOT 4096
#define L_LEN 128
#define D_DIM 200
#define A_DIM 20
#define NEGK  2
#define B_SZ  1024
#define NNZ_C 20480
#define RN_TOT (R_TOT*NEGK)
#define S_TOT (R_TOT + RN_TOT)
#define VOCAB_C 32000
#define EPS_ 1e-12f
#define SLOT_CAP 64          // Poisson(20) max bin ~45; 64 is safe
#define NBUCK_BLK 160        // 160*256 = 40960 = 2*NNZ_C
#define NREV 4               // reviews per k_attn block (pipelined)

__device__ __forceinline__ float4 unpack4(const uint2 u) {
  union { unsigned v; __half2 h; } c0, c1;
  c0.v = u.x; c1.v = u.y;
  const float2 f0 = __half22float2(c0.h);
  const float2 f1 = __half22float2(c1.h);
  return make_float4(f0.x, f0.y, f1.x, f1.y);
}

// ---------------- K0: cast emb -> fp16 table; block 0 also zeroes bucket counters ----------------
__global__ __launch_bounds__(256) void k_cast(
    const float* __restrict__ emb, ushort* __restrict__ emb_h, int* __restrict__ cnt)
{
  if (blockIdx.x == 0) {
    for (int i = threadIdx.x; i < 2*B_SZ; i += 256) cnt[i] = 0;
  }
  const int idx = blockIdx.x*256 + threadIdx.x;
  if (idx < (VOCAB_C*D_DIM)/4) {
    const float4 v = reinterpret_cast<const float4*>(emb)[idx];
    ushort4 o;
    o.x = __half_as_ushort(__float2half(v.x));
    o.y = __half_as_ushort(__float2half(v.y));
    o.z = __half_as_ushort(__float2half(v.z));
    o.w = __half_as_ushort(__float2half(v.w));
    reinterpret_cast<ushort4*>(emb_h)[idx] = o;
  }
}

// ---------------- K1: means (pos+neg) + FOLDED matvec (pos: vv = y_s @ Wm) + bucket tail ----------------
// Pos blocks: gather/sum -> y_s (LDS) -> vv[k] = sum_d y_s[d]*Wm[d,k] -> vv_all.
// Identical summation order to the old k_matvec -> bitwise-identical vv.
// Neg blocks: mean -> zn_all. Wm reads are L2-resident and overlap other blocks' gathers.
__global__ __launch_bounds__(256, 8) void k_means2(
    const int* __restrict__ hist, const int* __restrict__ neg,
    const ushort* __restrict__ emb_h, const float* __restrict__ Wm,
    float* __restrict__ vv_all, float* __restrict__ zn_all,
    const int* __restrict__ uidx, const float* __restrict__ uval,
    const int* __restrict__ iidx, const float* __restrict__ ival,
    int* __restrict__ cnt, int* __restrict__ scol, float* __restrict__ sval)
{
  const int sb = blockIdx.x;
  const int tid = threadIdx.x;

  if (sb >= S_TOT) {
    const int g = (sb - S_TOT)*256 + tid;
    if (g < NNZ_C) {
      const int b = uidx[g];
      const int slot = atomicAdd(&cnt[b], 1);
      if (slot < SLOT_CAP) {
        scol[b*SLOT_CAP + slot] = uidx[NNZ_C + g];
        sval[b*SLOT_CAP + slot] = uval[g];
      }
    } else {
      const int g2 = g - NNZ_C;
      const int b = iidx[g2];
      const int slot = atomicAdd(&cnt[B_SZ + b], 1);
      if (slot < SLOT_CAP) {
        scol[(B_SZ + b)*SLOT_CAP + slot] = iidx[NNZ_C + g2];
        sval[(B_SZ + b)*SLOT_CAP + slot] = ival[g2];
      }
    }
    return;
  }

  __shared__ int widx[L_LEN];
  __shared__ __align__(16) float part[8][D_DIM];
  __shared__ __align__(16) float ysm[D_DIM];
  const bool is_pos = (sb < R_TOT);
  const int* src = is_pos ? (hist + (size_t)sb*L_LEN)
                          : (neg + (size_t)(sb - R_TOT)*L_LEN);
  if (tid < L_LEN) widx[tid] = src[tid];
  __syncthreads();

  const int c5 = tid & 31;       // column chunk (active if < 25)
  const int j  = tid >> 5;       // 0..7 row group
  float4 sA = {0.f,0.f,0.f,0.f}, sB = {0.f,0.f,0.f,0.f};
  if (c5 < 25) {
    const size_t coff = 8*c5;
    #pragma unroll
    for (int k0 = 0; k0 < 16; k0 += 4) {
      const uint4 q0 = *reinterpret_cast<const uint4*>(
          emb_h + (size_t)widx[j + 8*(k0+0)]*D_DIM + coff);
      const uint4 q1 = *reinterpret_cast<const uint4*>(
          emb_h + (size_t)widx[j + 8*(k0+1)]*D_DIM + coff);
      const uint4 q2 = *reinterpret_cast<const uint4*>(
          emb_h + (size_t)widx[j + 8*(k0+2)]*D_DIM + coff);
      const uint4 q3 = *reinterpret_cast<const uint4*>(
          emb_h + (size_t)widx[j + 8*(k0+3)]*D_DIM + coff);
      float4 e;
      e = unpack4(make_uint2(q0.x,q0.y)); sA.x+=e.x; sA.y+=e.y; sA.z+=e.z; sA.w+=e.w;
      e = unpack4(make_uint2(q0.z,q0.w)); sB.x+=e.x; sB.y+=e.y; sB.z+=e.z; sB.w+=e.w;
      e = unpack4(make_uint2(q1.x,q1.y)); sA.x+=e.x; sA.y+=e.y; sA.z+=e.z; sA.w+=e.w;
      e = unpack4(make_uint2(q1.z,q1.w)); sB.x+=e.x; sB.y+=e.y; sB.z+=e.z; sB.w+=e.w;
      e = unpack4(make_uint2(q2.x,q2.y)); sA.x+=e.x; sA.y+=e.y; sA.z+=e.z; sA.w+=e.w;
      e = unpack4(make_uint2(q2.z,q2.w)); sB.x+=e.x; sB.y+=e.y; sB.z+=e.z; sB.w+=e.w;
      e = unpack4(make_uint2(q3.x,q3.y)); sA.x+=e.x; sA.y+=e.y; sA.z+=e.z; sA.w+=e.w;
      e = unpack4(make_uint2(q3.z,q3.w)); sB.x+=e.x; sB.y+=e.y; sB.z+=e.z; sB.w+=e.w;
    }
    *reinterpret_cast<float4*>(&part[j][8*c5])     = sA;
    *reinterpret_cast<float4*>(&part[j][8*c5 + 4]) = sB;
  }
  __syncthreads();

  if (is_pos) {
    if (tid < D_DIM) {
      float a = 0.f;
      #pragma unroll
      for (int j2 = 0; j2 < 8; ++j2) a += part[j2][tid];
      ysm[tid] = a * (1.0f/128.0f);
    }
    __syncthreads();
    if (tid < D_DIM) {
      float acc = 0.f;
      #pragma unroll 4
      for (int d = 0; d < D_DIM; ++d) acc += ysm[d] * Wm[d*D_DIM + tid];
      vv_all[(size_t)sb*D_DIM + tid] = acc;
    }
  } else {
    if (tid < D_DIM) {
      float a = 0.f;
      #pragma unroll
      for (int j2 = 0; j2 < 8; ++j2) a += part[j2][tid];
      zn_all[(size_t)(sb - R_TOT)*D_DIM + tid] = a * (1.0f/128.0f);
    }
  }
}

// ---------------- K3: pipelined attn — NREV reviews/block, register prefetch of next tile ----------------
// Per review: ONE gather pass (dx computed during LDS staging from prefetched regs),
// z_s from LDS. While review i runs softmax/z_s/p_t/r_s, review i+1's 8 uint4
// gathers are in flight in REGISTERS. launch_bounds(512,4) -> VGPR cap 128 so the
// ~95-reg held state does NOT spill (R3 lesson: (512,6) spilled 1.1 GB to scratch).
// LDS 53.4 KB; occupancy 2 blocks/CU (VGPR-bound) — acceptable, latency is hidden in-thread.
__global__ __launch_bounds__(512, 4) void k_attn(
    const int* __restrict__ hist, const ushort* __restrict__ emb_h,
    const float* __restrict__ vv_all,
    const float* __restrict__ Ww, const float* __restrict__ bw,
    const float* __restrict__ Wt, const float* __restrict__ zn_all,
    float* __restrict__ rs_out, float* __restrict__ abae)
{
  __shared__ __align__(16) ushort ew[L_LEN*D_DIM];   // 51200 B, (L,D) row-major fp16
  __shared__ __align__(16) float ax[L_LEN];          // 512 B
  __shared__ __align__(16) float zs[D_DIM];          // 800 B
  __shared__ __align__(16) float ubuf[240];          // 960 B: ptile [0..160), red [160..240)
  float* ptile = ubuf;
  float* red   = ubuf + 160;

  const int tid = threadIdx.x, lane = tid & 63, wv = tid >> 6;
  const int c5 = tid & 31;      // column chunk (active if < 25)
  const int j  = tid >> 5;      // 0..15 row group
  const bool act = (c5 < 25);
  const int coff = 8*c5;
  const int r0 = blockIdx.x * NREV;

  // ---- prologue: widx + tile gathers + vv for review r0 ----
  uint4 q0,q1,q2,q3,q4,q5,q6,q7;
  q0=q1=q2=q3=q4=q5=q6=q7=make_uint4(0,0,0,0);
  float4 v8a = {0,0,0,0}, v8b = {0,0,0,0};
  if (act) {
    const int base = r0*L_LEN + j;
    const int w0 = hist[base],     w1 = hist[base+16], w2 = hist[base+32], w3 = hist[base+48];
    const int w4 = hist[base+64],  w5 = hist[base+80], w6 = hist[base+96], w7 = hist[base+112];
    q0 = *reinterpret_cast<const uint4*>(emb_h + (size_t)w0*D_DIM + coff);
    q1 = *reinterpret_cast<const uint4*>(emb_h + (size_t)w1*D_DIM + coff);
    q2 = *reinterpret_cast<const uint4*>(emb_h + (size_t)w2*D_DIM + coff);
    q3 = *reinterpret_cast<const uint4*>(emb_h + (size_t)w3*D_DIM + coff);
    q4 = *reinterpret_cast<const uint4*>(emb_h + (size_t)w4*D_DIM + coff);
    q5 = *reinterpret_cast<const uint4*>(emb_h + (size_t)w5*D_DIM + coff);
    q6 = *reinterpret_cast<const uint4*>(emb_h + (size_t)w6*D_DIM + coff);
    q7 = *reinterpret_cast<const uint4*>(emb_h + (size_t)w7*D_DIM + coff);
    v8a = *reinterpret_cast<const float4*>(vv_all + (size_t)r0*D_DIM + coff);
    v8b = *reinterpret_cast<const float4*>(vv_all + (size_t)r0*D_DIM + coff + 4);
  }

  for (int i = 0; i < NREV; ++i) {
    const int r = r0 + i;

    __syncthreads();   // previous iteration's ew readers are done

    // ---- stage tile from regs to LDS + dx partials ----
    float p0=0.f,p1=0.f,p2=0.f,p3=0.f,p4=0.f,p5=0.f,p6=0.f,p7=0.f;
    if (act) {
      #define STG(K, Q, P) { \
        *reinterpret_cast<uint4*>(ew + (j + 16*(K))*D_DIM + coff) = Q; \
        const float4 e0_ = unpack4(make_uint2(Q.x, Q.y)); \
        const float4 e1_ = unpack4(make_uint2(Q.z, Q.w)); \
        P = e0_.x*v8a.x + e0_.y*v8a.y + e0_.z*v8a.z + e0_.w*v8a.w \
          + e1_.x*v8b.x + e1_.y*v8b.y + e1_.z*v8b.z + e1_.w*v8b.w; }
      STG(0,q0,p0) STG(1,q1,p1) STG(2,q2,p2) STG(3,q3,p3)
      STG(4,q4,p4) STG(5,q5,p5) STG(6,q6,p6) STG(7,q7,p7)
      #undef STG
      // refill prefetch regs for review r+1: widx loads then row gathers; the
      // gathers have the entire serial phase (softmax/z_s/p_t/r_s) to land.
      if (i < NREV-1) {
        const int nb = (r+1)*L_LEN + j;
        const int w0n = hist[nb],     w1n = hist[nb+16], w2n = hist[nb+32], w3n = hist[nb+48];
        const int w4n = hist[nb+64],  w5n = hist[nb+80], w6n = hist[nb+96], w7n = hist[nb+112];
        q0 = *reinterpret_cast<const uint4*>(emb_h + (size_t)w0n*D_DIM + coff);
        q1 = *reinterpret_cast<const uint4*>(emb_h + (size_t)w1n*D_DIM + coff);
        q2 = *reinterpret_cast<const uint4*>(emb_h + (size_t)w2n*D_DIM + coff);
        q3 = *reinterpret_cast<const uint4*>(emb_h + (size_t)w3n*D_DIM + coff);
        q4 = *reinterpret_cast<const uint4*>(emb_h + (size_t)w4n*D_DIM + coff);
        q5 = *reinterpret_cast<const uint4*>(emb_h + (size_t)w5n*D_DIM + coff);
        q6 = *reinterpret_cast<const uint4*>(emb_h + (size_t)w6n*D_DIM + coff);
        q7 = *reinterpret_cast<const uint4*>(emb_h + (size_t)w7n*D_DIM + coff);
      }
    }
    // prefetch next vv + current zn rows (used after z_s)
    float4 v8an = {0,0,0,0}, v8bn = {0,0,0,0};
    if (act && i < NREV-1) {
      v8an = *reinterpret_cast<const float4*>(vv_all + (size_t)(r+1)*D_DIM + coff);
      v8bn = *reinterpret_cast<const float4*>(vv_all + (size_t)(r+1)*D_DIM + coff + 4);
    }
    float zn0 = 0.f, zn1 = 0.f;
    if (tid < D_DIM) {
      zn0 = zn_all[(size_t)(2*r)*D_DIM + tid];
      zn1 = zn_all[(size_t)(2*r + 1)*D_DIM + tid];
    }

    // dx reduce over the 25 active c5 lanes of each half-wave (inactive lanes hold 0)
    #pragma unroll
    for (int o = 16; o > 0; o >>= 1) {
      p0 += __shfl_xor(p0, o); p1 += __shfl_xor(p1, o);
      p2 += __shfl_xor(p2, o); p3 += __shfl_xor(p3, o);
      p4 += __shfl_xor(p4, o); p5 += __shfl_xor(p5, o);
      p6 += __shfl_xor(p6, o); p7 += __shfl_xor(p7, o);
    }
    if (c5 == 0) {
      ax[j]      = p0; ax[j + 16]  = p1; ax[j + 32]  = p2; ax[j + 48]  = p3;
      ax[j + 64] = p4; ax[j + 80]  = p5; ax[j + 96]  = p6; ax[j + 112] = p7;
    }
    __syncthreads();

    // ---- softmax over 128 (wave 0 reduces) ----
    if (tid < 64) {
      float m = fmaxf(ax[tid], ax[tid+64]);
      #pragma unroll
      for (int o = 32; o > 0; o >>= 1) m = fmaxf(m, __shfl_xor(m, o));
      if (tid == 0) red[0] = m;
    }
    __syncthreads();
    const float M = red[0];
    if (tid < L_LEN) ax[tid] = expf(ax[tid] - M);
    __syncthreads();
    if (tid < 64) {
      float s = ax[tid] + ax[tid+64];
      #pragma unroll
      for (int o = 32; o > 0; o >>= 1) s += __shfl_xor(s, o);
      if (tid == 0) red[1] = s;
    }
    __syncthreads();
    const float Sinv = 1.0f / red[1];
    if (tid < L_LEN) ax[tid] *= Sinv;
    __syncthreads();

    // ---- z_s from LDS, flat (reshape) indexing; quarter-wave per d-window ----
    {
      const int lq = lane & 15;
      const int quad = lane >> 4;
      const float4 ax8a = *reinterpret_cast<const float4*>(ax + 8*lq);
      const float4 ax8b = *reinterpret_cast<const float4*>(ax + 8*lq + 4);
      for (int dq = wv; dq < 50; dq += 8) {
        const int d0 = 4*dq + quad;
        const int f0 = (d0 << 7) + 8*lq;      // flat half-index, 16B aligned
        const uint4 q = *reinterpret_cast<const uint4*>(ew + f0);
        const float4 e0 = unpack4(make_uint2(q.x, q.y));
        const float4 e1 = unpack4(make_uint2(q.z, q.w));
        float a = e0.x*ax8a.x + e0.y*ax8a.y + e0.z*ax8a.z + e0.w*ax8a.w
                + e1.x*ax8b.x + e1.y*ax8b.y + e1.z*ax8b.z + e1.w*ax8b.w;
        #pragma unroll
        for (int o = 8; o > 0; o >>= 1) a += __shfl_xor(a, o);
        if (lq == 0) zs[d0] = a;
      }
    }
    __syncthreads();

    // ---- p_t[a] = z_s . Ww[a,:] + bw[a] — 8x20 partials ----
    if (tid < 160) {
      const int a = tid % 20, jj = tid / 20;
      float s = 0.f;
      #pragma unroll
      for (int ii = 0; ii < 25; ++ii) {
        const int d = jj + 8*ii;
        s += zs[d] * Ww[a*D_DIM + d];
      }
      ptile[tid] = s;
    }
    __syncthreads();
    if (tid < A_DIM) {
      float s = bw[tid];
      #pragma unroll
      for (int jj = 0; jj < 8; ++jj) s += ptile[jj*20 + tid];
      red[2 + tid] = s;
    }
    __syncthreads();

    // ---- r_s + fused norms for c1 and both c2 rows ----
    float rsd = 0.f, zsd = 0.f;
    if (tid < D_DIM) {
      float acc = 0.f;
      #pragma unroll
      for (int a = 0; a < A_DIM; ++a) acc += red[2+a] * Wt[tid*A_DIM + a];
      rsd = acc; zsd = zs[tid];
      rs_out[(size_t)r*D_DIM + tid] = acc;
    } else { zn0 = 0.f; zn1 = 0.f; }
    float a0 = rsd*rsd, a1 = zsd*zsd, a2 = rsd*zsd;
    float b0 = zn0*zn0, b1 = zn0*rsd, b2 = zn1*zn1, b3 = zn1*rsd;
    #pragma unroll
    for (int o = 32; o > 0; o >>= 1) {
      a0 += __shfl_xor(a0, o); a1 += __shfl_xor(a1, o); a2 += __shfl_xor(a2, o);
      b0 += __shfl_xor(b0, o); b1 += __shfl_xor(b1, o);
      b2 += __shfl_xor(b2, o); b3 += __shfl_xor(b3, o);
    }
    if ((tid & 63) == 0) {
      red[22+wv] = a0; red[30+wv] = a1; red[38+wv] = a2;
      red[46+wv] = b0; red[54+wv] = b1; red[62+wv] = b2; red[70+wv] = b3;
    }
    __syncthreads();
    if (tid == 0) {
      float s0=0.f,s1=0.f,s2=0.f,t0=0.f,t1=0.f,t2=0.f,t3=0.f;
      #pragma unroll
      for (int ii = 0; ii < 8; ++ii) {
        s0 += red[22+ii]; s1 += red[30+ii]; s2 += red[38+ii];
        t0 += red[46+ii]; t1 += red[54+ii]; t2 += red[62+ii]; t3 += red[70+ii];
      }
      const float nr = fmaxf(sqrtf(s0), EPS_);
      const float nz = fmaxf(sqrtf(s1), EPS_);
      const float c1 = s2 / (nr * nz);
      const float c2a = t1 / (fmaxf(sqrtf(t0), EPS_) * nr);
      const float c2b = t3 / (fmaxf(sqrtf(t2), EPS_) * nr);
      abae[2*r]     = fmaxf(c2a - c1 + 1.0f, 0.0f);
      abae[2*r + 1] = fmaxf(c2b - c1 + 1.0f, 0.0f);
    }

    // rotate vv prefetch
    v8a = v8an; v8b = v8bn;
  }
}

// ---------------- K4: merged segment-sum apply + FM (one block per b) ----------------
__global__ __launch_bounds__(512) void k_aggfm(
    const int* __restrict__ cnt, const int* __restrict__ scol,
    const float* __restrict__ sval, const float* __restrict__ rs,
    const float* __restrict__ fcw, const float* __restrict__ V,
    float* __restrict__ uae, float* __restrict__ iae,
    float* __restrict__ linb, float* __restrict__ quadb)
{
  __shared__ __align__(16) float ivec[2*D_DIM];
  __shared__ float redw[8];
  __shared__ float qpart[10];
  const int b = blockIdx.x;
  const int tid = threadIdx.x, lane = tid & 63, wv = tid >> 6;

  if (tid < D_DIM) {
    int n = cnt[b]; n = n < SLOT_CAP ? n : SLOT_CAP;
    const int* cols = scol + (size_t)b*SLOT_CAP;
    const float* vals = sval + (size_t)b*SLOT_CAP;
    float acc = 0.f;
    for (int j = 0; j < n; ++j) acc += vals[j] * rs[(size_t)cols[j]*D_DIM + tid];
    ivec[tid] = acc;
    uae[(size_t)b*D_DIM + tid] = acc;
  } else if (tid >= 256 && tid < 256 + D_DIM) {
    const int t = tid - 256;
    int n = cnt[B_SZ + b]; n = n < SLOT_CAP ? n : SLOT_CAP;
    const int* cols = scol + (size_t)(B_SZ + b)*SLOT_CAP;
    const float* vals = sval + (size_t)(B_SZ + b)*SLOT_CAP;
    float acc = 0.f;
    for (int j = 0; j < n; ++j) acc += vals[j] * rs[(size_t)cols[j]*D_DIM + t];
    ivec[D_DIM + t] = acc;
    iae[(size_t)b*D_DIM + t] = acc;
  }
  __syncthreads();

  float lv = 0.f;
  if (tid < 2*D_DIM) lv = ivec[tid] * fcw[tid];
  #pragma unroll
  for (int o = 32; o > 0; o >>= 1) lv += __shfl_xor(lv, o);
  if (lane == 0) redw[wv] = lv;

  {
    const int k = wv;
    float s1 = 0.f, s2 = 0.f;
    for (int f = lane; f < 2*D_DIM; f += 64) {
      const float x = ivec[f];
      const float vk = V[f*10 + k];
      s1 += x*vk; s2 += x*x*vk*vk;
    }
    #pragma unroll
    for (int o = 32; o > 0; o >>= 1) { s1 += __shfl_xor(s1,o); s2 += __shfl_xor(s2,o); }
    if (lane == 0) qpart[k] = s1*s1 - s2;
  }
  if (wv < 2) {
    const int k = 8 + wv;
    float s1 = 0.f, s2 = 0.f;
    for (int f = lane; f < 2*D_DIM; f += 64) {
      const float x = ivec[f];
      const float vk = V[f*10 + k];
      s1 += x*vk; s2 += x*x*vk*vk;
    }
    #pragma unroll
    for (int o = 32; o > 0; o >>= 1) { s1 += __shfl_xor(s1,o); s2 += __shfl_xor(s2,o); }
    if (lane == 0) qpart[k] = s1*s1 - s2;
  }
  __syncthreads();
  if (tid == 0) {
    float lin = 0.f;
    #pragma unroll
    for (int i = 0; i < 8; ++i) lin += redw[i];
    float q = 0.f;
    #pragma unroll
    for (int i = 0; i < 10; ++i) q += qpart[i];
    linb[b] = lin; quadb[b] = q;
  }
}

// ---------------- K5: fused quad-reduce + prediction + all final scalars ----------------
__global__ __launch_bounds__(1024) void k_final2(
    const float* __restrict__ quadb, const float* __restrict__ linb,
    const float* __restrict__ fcb, const int* __restrict__ user,
    const int* __restrict__ item, const float* __restrict__ busers,
    const float* __restrict__ bitems, const float* __restrict__ label,
    const float* __restrict__ Wt, const float* __restrict__ abae,
    float* __restrict__ pred, float* __restrict__ rl, float* __restrict__ obj)
{
  __shared__ float sA[16], sB[16], sC[16];
  __shared__ float cninv[A_DIM];
  __shared__ float quad_s;
  const int tid = threadIdx.x;
  const int lane = tid & 63;
  const int wv = tid >> 6;

  float q = quadb[tid];
  #pragma unroll
  for (int o = 32; o > 0; o >>= 1) q += __shfl_xor(q, o);
  if (lane == 0) sA[wv] = q;

  if (tid < A_DIM) {
    float s = 0.f;
    for (int d = 0; d < D_DIM; ++d) { const float w = Wt[d*A_DIM + tid]; s += w*w; }
    cninv[tid] = 1.0f / fmaxf(sqrtf(s), EPS_);
  }
  __syncthreads();
  if (wv == 0) {
    float s = (lane < 16) ? sA[lane] : 0.f;
    #pragma unroll
    for (int o = 32; o > 0; o >>= 1) s += __shfl_xor(s, o);
    if (lane == 0) quad_s = s;
  }
  __syncthreads();

  const float p = 0.5f*quad_s + linb[tid] + fcb[0]
                + busers[user[tid]] + bitems[item[tid]];
  pred[tid] = p;
  const float dd = p - label[tid];
  const float myrl = dd*dd;
  rl[tid] = myrl;

  float u = 0.f;
  if (tid < 400) {
    const int a = tid / 20, c = tid % 20;
    float dot = 0.f;
    for (int d = 0; d < D_DIM; ++d) dot += Wt[d*A_DIM + a]*Wt[d*A_DIM + c];
    const float g = dot*cninv[a]*cninv[c] - (a==c ? 1.0f : 0.0f);
    u = g*g;
  }
  float js = 0.f;
  #pragma unroll
  for (int j = 0; j < 8; ++j) js += abae[tid + 1024*j];
  float ms = myrl;

  #pragma unroll
  for (int o = 32; o > 0; o >>= 1) {
    u += __shfl_xor(u,o); js += __shfl_xor(js,o); ms += __shfl_xor(ms,o);
  }
  if (lane == 0) { sA[wv] = u; sB[wv] = js; sC[wv] = ms; }
  __syncthreads();
  if (tid == 0) {
    float U = 0.f, J = 0.f, Ms = 0.f;
    for (int i = 0; i < 16; ++i) { U += sA[i]; J += sB[i]; Ms += sC[i]; }
    obj[0] = Ms/1024.0f + 0.01f*(J/8192.0f) + 0.01f*(U/400.0f);
  }
}

extern "C" void kernel_launch(void* const* d_in, const int* in_sizes, int n_in,
                              void* d_out, int out_size, void* d_ws, size_t ws_size,
                              hipStream_t stream) {
  const int*   hist   = (const int*)  d_in[0];
  const int*   neg    = (const int*)  d_in[1];
  const int*   user   = (const int*)  d_in[2];
  const int*   item   = (const int*)  d_in[3];
  const float* label  = (const float*)d_in[4];
  const int*   uidx   = (const int*)  d_in[5];
  const float* uval   = (const float*)d_in[6];
  const int*   iidx   = (const int*)  d_in[7];
  const float* ival   = (const float*)d_in[8];
  const float* emb    = (const float*)d_in[9];
  const float* Wm     = (const float*)d_in[10];
  const float* Ww     = (const float*)d_in[11];
  const float* bw     = (const float*)d_in[12];
  const float* Wt     = (const float*)d_in[13];
  const float* fcw    = (const float*)d_in[14];
  const float* fcb    = (const float*)d_in[15];
  const float* V      = (const float*)d_in[16];
  const float* busers = (const float*)d_in[17];
  const float* bitems = (const float*)d_in[18];

  float* out  = (float*)d_out;
  float* obj  = out;                       // 1
  float* rl   = out + 1;                   // 1024
  float* abae = out + 1 + B_SZ;            // 8192
  float* pred = out + 1 + B_SZ + RN_TOT;   // 1024
  float* uae  = pred + B_SZ;               // 204800
  float* iae  = uae + (size_t)B_SZ*D_DIM;  // 204800

  float* ws     = (float*)d_ws;
  float* rs     = ws;                              // R*D
  float* zn_all = rs + (size_t)R_TOT*D_DIM;        // RN*D
  float* vv_all = zn_all + (size_t)RN_TOT*D_DIM;   // R*D
  float* linb   = vv_all + (size_t)R_TOT*D_DIM;    // B
  float* quadb  = linb + B_SZ;                     // B
  float* sval   = quadb + B_SZ;                    // 2*B*SLOT_CAP floats
  int*   scol   = (int*)(sval + (size_t)2*B_SZ*SLOT_CAP);   // 2*B*SLOT_CAP ints
  int*   cnt    = scol + (size_t)2*B_SZ*SLOT_CAP;           // 2*B ints
  ushort* emb_h = (ushort*)(cnt + 2*B_SZ);                  // VOCAB*D halves

  const int cast_blocks = (VOCAB_C*D_DIM/4 + 255)/256;      // 6250

  k_cast  <<<cast_blocks, 256, 0, stream>>>(emb, emb_h, cnt);
  k_means2<<<S_TOT + NBUCK_BLK, 256, 0, stream>>>(hist, neg, emb_h, Wm,
                                                  vv_all, zn_all,
                                                  uidx, uval, iidx, ival,
                                                  cnt, scol, sval);
  k_attn  <<<R_TOT/NREV, 512, 0, stream>>>(hist, emb_h, vv_all, Ww, bw, Wt,
                                           zn_all, rs, abae);
  k_aggfm <<<B_SZ, 512, 0, stream>>>(cnt, scol, sval, rs, fcw, V,
                                     uae, iae, linb, quadb);
  k_final2<<<1, 1024, 0, stream>>>(quadb, linb, fcb, user, item, busers, bitems,
                                   label, Wt, abae, pred, rl, obj);
}

// Round 5
// 309.203 us; speedup vs baseline: 2.0390x; 1.0592x over previous
//
#include <hip/hip_runtime.h>
#include <hip/hip_fp16.h>
#include <math.h>

// Problem constants (match reference)
#define R_TOT 4096
#define L_LEN 128
#define D_DIM 200
#define A_DIM 20
#define NEGK  2
#define B_SZ  1024
#define NNZ_C 20480
#define RN_TOT (R_TOT*NEGK)
#define S_TOT (R_TOT + RN_TOT)
#define VOCAB_C 32000
#define EPS_ 1e-12f
#define SLOT_CAP 64          // Poisson(20) max bin ~45; 64 is safe
#define NBUCK_BLK 160        // 160*256 = 40960 = 2*NNZ_C

__device__ __forceinline__ float4 unpack4(const uint2 u) {
  union { unsigned v; __half2 h; } c0, c1;
  c0.v = u.x; c1.v = u.y;
  const float2 f0 = __half22float2(c0.h);
  const float2 f1 = __half22float2(c1.h);
  return make_float4(f0.x, f0.y, f1.x, f1.y);
}

// ---------------- K0: cast emb -> fp16 table; block 0 also zeroes bucket counters ----------------
__global__ __launch_bounds__(256) void k_cast(
    const float* __restrict__ emb, ushort* __restrict__ emb_h, int* __restrict__ cnt)
{
  if (blockIdx.x == 0) {
    for (int i = threadIdx.x; i < 2*B_SZ; i += 256) cnt[i] = 0;
  }
  const int idx = blockIdx.x*256 + threadIdx.x;
  if (idx < (VOCAB_C*D_DIM)/4) {
    const float4 v = reinterpret_cast<const float4*>(emb)[idx];
    ushort4 o;
    o.x = __half_as_ushort(__float2half(v.x));
    o.y = __half_as_ushort(__float2half(v.y));
    o.z = __half_as_ushort(__float2half(v.z));
    o.w = __half_as_ushort(__float2half(v.w));
    reinterpret_cast<ushort4*>(emb_h)[idx] = o;
  }
}

// ---------------- K1: combined means (pos+neg) + bucket tail ----------------
// 8-deep independent uint4 gathers per thread (2x MLP vs R2's 4-deep).
// Thread (j = tid>>5 in 0..7, c5 = tid&31 < 25): rows l = j + 8k, cols 8c5..8c5+7.
#define ACC8(Q) { \
  const float4 e0_ = unpack4(make_uint2((Q).x,(Q).y)); \
  const float4 e1_ = unpack4(make_uint2((Q).z,(Q).w)); \
  sA.x+=e0_.x; sA.y+=e0_.y; sA.z+=e0_.z; sA.w+=e0_.w; \
  sB.x+=e1_.x; sB.y+=e1_.y; sB.z+=e1_.z; sB.w+=e1_.w; }

__global__ __launch_bounds__(256, 8) void k_means2(
    const int* __restrict__ hist, const int* __restrict__ neg,
    const ushort* __restrict__ emb_h,
    float* __restrict__ ys_all, float* __restrict__ zn_all,
    const int* __restrict__ uidx, const float* __restrict__ uval,
    const int* __restrict__ iidx, const float* __restrict__ ival,
    int* __restrict__ cnt, int* __restrict__ scol, float* __restrict__ sval)
{
  const int sb = blockIdx.x;
  const int tid = threadIdx.x;

  if (sb >= S_TOT) {
    const int g = (sb - S_TOT)*256 + tid;
    if (g < NNZ_C) {
      const int b = uidx[g];
      const int slot = atomicAdd(&cnt[b], 1);
      if (slot < SLOT_CAP) {
        scol[b*SLOT_CAP + slot] = uidx[NNZ_C + g];
        sval[b*SLOT_CAP + slot] = uval[g];
      }
    } else {
      const int g2 = g - NNZ_C;
      const int b = iidx[g2];
      const int slot = atomicAdd(&cnt[B_SZ + b], 1);
      if (slot < SLOT_CAP) {
        scol[(B_SZ + b)*SLOT_CAP + slot] = iidx[NNZ_C + g2];
        sval[(B_SZ + b)*SLOT_CAP + slot] = ival[g2];
      }
    }
    return;
  }

  __shared__ int widx[L_LEN];
  __shared__ __align__(16) float part[8][D_DIM];
  const bool is_pos = (sb < R_TOT);
  const int* src = is_pos ? (hist + (size_t)sb*L_LEN)
                          : (neg + (size_t)(sb - R_TOT)*L_LEN);
  if (tid < L_LEN) widx[tid] = src[tid];
  __syncthreads();

  const int c5 = tid & 31;       // column chunk (active if < 25)
  const int j  = tid >> 5;       // 0..7 row group
  float4 sA = {0.f,0.f,0.f,0.f}, sB = {0.f,0.f,0.f,0.f};
  if (c5 < 25) {
    const size_t coff = 8*c5;
    // batch 1: 8 loads in flight, then consume
    uint4 q0 = *reinterpret_cast<const uint4*>(emb_h + (size_t)widx[j +   0]*D_DIM + coff);
    uint4 q1 = *reinterpret_cast<const uint4*>(emb_h + (size_t)widx[j +   8]*D_DIM + coff);
    uint4 q2 = *reinterpret_cast<const uint4*>(emb_h + (size_t)widx[j +  16]*D_DIM + coff);
    uint4 q3 = *reinterpret_cast<const uint4*>(emb_h + (size_t)widx[j +  24]*D_DIM + coff);
    uint4 q4 = *reinterpret_cast<const uint4*>(emb_h + (size_t)widx[j +  32]*D_DIM + coff);
    uint4 q5 = *reinterpret_cast<const uint4*>(emb_h + (size_t)widx[j +  40]*D_DIM + coff);
    uint4 q6 = *reinterpret_cast<const uint4*>(emb_h + (size_t)widx[j +  48]*D_DIM + coff);
    uint4 q7 = *reinterpret_cast<const uint4*>(emb_h + (size_t)widx[j +  56]*D_DIM + coff);
    ACC8(q0) ACC8(q1) ACC8(q2) ACC8(q3) ACC8(q4) ACC8(q5) ACC8(q6) ACC8(q7)
    // batch 2
    q0 = *reinterpret_cast<const uint4*>(emb_h + (size_t)widx[j +  64]*D_DIM + coff);
    q1 = *reinterpret_cast<const uint4*>(emb_h + (size_t)widx[j +  72]*D_DIM + coff);
    q2 = *reinterpret_cast<const uint4*>(emb_h + (size_t)widx[j +  80]*D_DIM + coff);
    q3 = *reinterpret_cast<const uint4*>(emb_h + (size_t)widx[j +  88]*D_DIM + coff);
    q4 = *reinterpret_cast<const uint4*>(emb_h + (size_t)widx[j +  96]*D_DIM + coff);
    q5 = *reinterpret_cast<const uint4*>(emb_h + (size_t)widx[j + 104]*D_DIM + coff);
    q6 = *reinterpret_cast<const uint4*>(emb_h + (size_t)widx[j + 112]*D_DIM + coff);
    q7 = *reinterpret_cast<const uint4*>(emb_h + (size_t)widx[j + 120]*D_DIM + coff);
    ACC8(q0) ACC8(q1) ACC8(q2) ACC8(q3) ACC8(q4) ACC8(q5) ACC8(q6) ACC8(q7)
    *reinterpret_cast<float4*>(&part[j][8*c5])     = sA;
    *reinterpret_cast<float4*>(&part[j][8*c5 + 4]) = sB;
  }
  __syncthreads();
  float* dst = is_pos ? (ys_all + (size_t)sb*D_DIM)
                      : (zn_all + (size_t)(sb - R_TOT)*D_DIM);
  if (tid < D_DIM) {
    float a = 0.f;
    #pragma unroll
    for (int j2 = 0; j2 < 8; ++j2) a += part[j2][tid];
    dst[tid] = a * (1.0f/128.0f);
  }
}

// ---------------- K2: V = Y @ Wm (16 reviews/block) ----------------
#define KB_RT 16
__global__ __launch_bounds__(256, 2) void k_matvec(
    const float* __restrict__ ys_all, const float* __restrict__ Wm,
    float* __restrict__ vv_all)
{
  __shared__ float ysl[KB_RT][D_DIM];
  const int r0 = blockIdx.x * KB_RT;
  const int tid = threadIdx.x;
  for (int i = tid; i < KB_RT*D_DIM; i += 256)
    ysl[i / D_DIM][i % D_DIM] = ys_all[(size_t)r0*D_DIM + i];
  __syncthreads();
  if (tid < D_DIM) {
    float acc[KB_RT];
    #pragma unroll
    for (int r = 0; r < KB_RT; ++r) acc[r] = 0.f;
    #pragma unroll 4
    for (int k = 0; k < D_DIM; ++k) {
      const float w = Wm[k*D_DIM + tid];
      #pragma unroll
      for (int r = 0; r < KB_RT; ++r) acc[r] += ysl[r][k] * w;
    }
    #pragma unroll
    for (int r = 0; r < KB_RT; ++r)
      vv_all[(size_t)(r0 + r)*D_DIM + tid] = acc[r];
  }
}

// ---------------- K3: attn — one gather pass, shortened serial chain (8 barriers) ----------------
// Staging+dx fused; exp fused with partial-sum; softmax normalization deferred into
// the z_s write (z_s linear in ax); epilogue reduced in parallel by 56 lanes.
// zn rows prefetched during staging. LDS 53.4 KB -> 3 blocks/CU.
__global__ __launch_bounds__(512, 4) void k_attn(
    const int* __restrict__ hist, const ushort* __restrict__ emb_h,
    const float* __restrict__ vv_all,
    const float* __restrict__ Ww, const float* __restrict__ bw,
    const float* __restrict__ Wt, const float* __restrict__ zn_all,
    float* __restrict__ rs_out, float* __restrict__ abae)
{
  __shared__ __align__(16) ushort ew[L_LEN*D_DIM];   // 51200 B, (L,D) row-major fp16
  __shared__ __align__(16) float ax[L_LEN];          // 512 B
  __shared__ __align__(16) float zs[D_DIM];          // 800 B
  __shared__ __align__(16) float ubuf[240];          // widx (staging) / ptile+red (after)
  int*   widx  = reinterpret_cast<int*>(ubuf);       // [0..128)
  float* ptile = ubuf;                               // [0..160)
  float* red   = ubuf + 160;                         // [160..240)

  const int r = blockIdx.x;
  const int tid = threadIdx.x, lane = tid & 63, wv = tid >> 6;
  const int c5 = tid & 31;      // column chunk (active if < 25)
  const int j  = tid >> 5;      // 0..15 row group
  const bool act = (c5 < 25);
  const int coff = 8*c5;

  if (tid < L_LEN) widx[tid] = hist[r*L_LEN + tid];
  float4 v8a = {0,0,0,0}, v8b = {0,0,0,0};
  if (act) {
    v8a = *reinterpret_cast<const float4*>(vv_all + (size_t)r*D_DIM + coff);
    v8b = *reinterpret_cast<const float4*>(vv_all + (size_t)r*D_DIM + coff + 4);
  }
  __syncthreads();                                   // B1

  // ---- staging (8 loads in flight) + zn prefetch + dx partials ----
  float zn0 = 0.f, zn1 = 0.f;
  float p0=0.f,p1=0.f,p2=0.f,p3=0.f,p4=0.f,p5=0.f,p6=0.f,p7=0.f;
  {
    uint4 q0,q1,q2,q3,q4,q5,q6,q7;
    if (act) {
      q0 = *reinterpret_cast<const uint4*>(emb_h + (size_t)widx[j +   0]*D_DIM + coff);
      q1 = *reinterpret_cast<const uint4*>(emb_h + (size_t)widx[j +  16]*D_DIM + coff);
      q2 = *reinterpret_cast<const uint4*>(emb_h + (size_t)widx[j +  32]*D_DIM + coff);
      q3 = *reinterpret_cast<const uint4*>(emb_h + (size_t)widx[j +  48]*D_DIM + coff);
      q4 = *reinterpret_cast<const uint4*>(emb_h + (size_t)widx[j +  64]*D_DIM + coff);
      q5 = *reinterpret_cast<const uint4*>(emb_h + (size_t)widx[j +  80]*D_DIM + coff);
      q6 = *reinterpret_cast<const uint4*>(emb_h + (size_t)widx[j +  96]*D_DIM + coff);
      q7 = *reinterpret_cast<const uint4*>(emb_h + (size_t)widx[j + 112]*D_DIM + coff);
    }
    if (tid < D_DIM) {                 // independent; lands during serial phases
      zn0 = zn_all[(size_t)(2*r)*D_DIM + tid];
      zn1 = zn_all[(size_t)(2*r + 1)*D_DIM + tid];
    }
    if (act) {
      #define STG(K, Q, P) { \
        *reinterpret_cast<uint4*>(ew + (j + 16*(K))*D_DIM + coff) = Q; \
        const float4 e0_ = unpack4(make_uint2(Q.x, Q.y)); \
        const float4 e1_ = unpack4(make_uint2(Q.z, Q.w)); \
        P = e0_.x*v8a.x + e0_.y*v8a.y + e0_.z*v8a.z + e0_.w*v8a.w \
          + e1_.x*v8b.x + e1_.y*v8b.y + e1_.z*v8b.z + e1_.w*v8b.w; }
      STG(0,q0,p0) STG(1,q1,p1) STG(2,q2,p2) STG(3,q3,p3)
      STG(4,q4,p4) STG(5,q5,p5) STG(6,q6,p6) STG(7,q7,p7)
      #undef STG
    }
  }
  // dx reduce over the 25 active c5 lanes of each half-wave (inactive lanes hold 0)
  #pragma unroll
  for (int o = 16; o > 0; o >>= 1) {
    p0 += __shfl_xor(p0, o); p1 += __shfl_xor(p1, o);
    p2 += __shfl_xor(p2, o); p3 += __shfl_xor(p3, o);
    p4 += __shfl_xor(p4, o); p5 += __shfl_xor(p5, o);
    p6 += __shfl_xor(p6, o); p7 += __shfl_xor(p7, o);
  }
  if (c5 == 0) {
    ax[j]      = p0; ax[j + 16]  = p1; ax[j + 32]  = p2; ax[j + 48]  = p3;
    ax[j + 64] = p4; ax[j + 80]  = p5; ax[j + 96]  = p6; ax[j + 112] = p7;
  }
  __syncthreads();                                   // B2 (widx dead after here)

  // ---- softmax max (wave 0) ----
  if (tid < 64) {
    float m = fmaxf(ax[tid], ax[tid+64]);
    #pragma unroll
    for (int o = 32; o > 0; o >>= 1) m = fmaxf(m, __shfl_xor(m, o));
    if (tid == 0) red[0] = m;
  }
  __syncthreads();                                   // B3
  // ---- exp + per-wave partial sum fused (waves 0,1) ----
  const float M = red[0];
  if (tid < L_LEN) {
    float e = expf(ax[tid] - M);
    ax[tid] = e;
    float s = e;
    #pragma unroll
    for (int o = 32; o > 0; o >>= 1) s += __shfl_xor(s, o);
    if (lane == 0) red[1 + wv] = s;
  }
  __syncthreads();                                   // B4

  // ---- z_s from LDS, normalization deferred to the write ----
  {
    const float Sinv = 1.0f / (red[1] + red[2]);
    const int lq = lane & 15;
    const int quad = lane >> 4;
    const float4 ax8a = *reinterpret_cast<const float4*>(ax + 8*lq);
    const float4 ax8b = *reinterpret_cast<const float4*>(ax + 8*lq + 4);
    for (int dq = wv; dq < 50; dq += 8) {
      const int d0 = 4*dq + quad;
      const int f0 = (d0 << 7) + 8*lq;      // flat half-index, 16B aligned
      const uint4 q = *reinterpret_cast<const uint4*>(ew + f0);
      const float4 e0 = unpack4(make_uint2(q.x, q.y));
      const float4 e1 = unpack4(make_uint2(q.z, q.w));
      float a = e0.x*ax8a.x + e0.y*ax8a.y + e0.z*ax8a.z + e0.w*ax8a.w
              + e1.x*ax8b.x + e1.y*ax8b.y + e1.z*ax8b.z + e1.w*ax8b.w;
      #pragma unroll
      for (int o = 8; o > 0; o >>= 1) a += __shfl_xor(a, o);
      if (lq == 0) zs[d0] = a * Sinv;
    }
  }
  __syncthreads();                                   // B5

  // ---- p_t[a] = z_s . Ww[a,:] + bw[a] — 8x20 partials ----
  if (tid < 160) {
    const int a = tid % 20, jj = tid / 20;
    float s = 0.f;
    #pragma unroll
    for (int ii = 0; ii < 25; ++ii) {
      const int d = jj + 8*ii;
      s += zs[d] * Ww[a*D_DIM + d];
    }
    ptile[tid] = s;
  }
  __syncthreads();                                   // B6
  if (tid < A_DIM) {
    float s = bw[tid];
    #pragma unroll
    for (int jj = 0; jj < 8; ++jj) s += ptile[jj*20 + tid];
    red[2 + tid] = s;
  }
  __syncthreads();                                   // B7

  // ---- r_s + fused norm partials (7 values, grouped slots red[22+8q+wv]) ----
  float rsd = 0.f, zsd = 0.f;
  if (tid < D_DIM) {
    float acc = 0.f;
    #pragma unroll
    for (int a = 0; a < A_DIM; ++a) acc += red[2+a] * Wt[tid*A_DIM + a];
    rsd = acc; zsd = zs[tid];
    rs_out[(size_t)r*D_DIM + tid] = acc;
  } else { zn0 = 0.f; zn1 = 0.f; }
  float a0 = rsd*rsd, a1 = zsd*zsd, a2 = rsd*zsd;
  float b0 = zn0*zn0, b1 = zn0*rsd, b2 = zn1*zn1, b3 = zn1*rsd;
  #pragma unroll
  for (int o = 32; o > 0; o >>= 1) {
    a0 += __shfl_xor(a0, o); a1 += __shfl_xor(a1, o); a2 += __shfl_xor(a2, o);
    b0 += __shfl_xor(b0, o); b1 += __shfl_xor(b1, o);
    b2 += __shfl_xor(b2, o); b3 += __shfl_xor(b3, o);
  }
  if (lane == 0) {
    red[22 + 0*8 + wv] = a0; red[22 + 1*8 + wv] = a1; red[22 + 2*8 + wv] = a2;
    red[22 + 3*8 + wv] = b0; red[22 + 4*8 + wv] = b1;
    red[22 + 5*8 + wv] = b2; red[22 + 6*8 + wv] = b3;
  }
  __syncthreads();                                   // B8

  // ---- parallel epilogue: 7 groups of 8 partials reduced by wave 0 ----
  if (tid < 64) {
    const int qi = tid >> 3, k = tid & 7;
    float v = (qi < 7) ? red[22 + 8*qi + k] : 0.f;
    v += __shfl_xor(v, 1); v += __shfl_xor(v, 2); v += __shfl_xor(v, 4);
    const float s0 = __shfl(v, 0),  s1 = __shfl(v, 8),  s2 = __shfl(v, 16);
    const float t0 = __shfl(v, 24), t1 = __shfl(v, 32);
    const float t2 = __shfl(v, 40), t3 = __shfl(v, 48);
    if (tid == 0) {
      const float nr = fmaxf(sqrtf(s0), EPS_);
      const float nz = fmaxf(sqrtf(s1), EPS_);
      const float c1 = s2 / (nr * nz);
      const float c2a = t1 / (fmaxf(sqrtf(t0), EPS_) * nr);
      const float c2b = t3 / (fmaxf(sqrtf(t2), EPS_) * nr);
      abae[2*r]     = fmaxf(c2a - c1 + 1.0f, 0.0f);
      abae[2*r + 1] = fmaxf(c2b - c1 + 1.0f, 0.0f);
    }
  }
}

// ---------------- K4: merged segment-sum apply + FM (one block per b) ----------------
__global__ __launch_bounds__(512) void k_aggfm(
    const int* __restrict__ cnt, const int* __restrict__ scol,
    const float* __restrict__ sval, const float* __restrict__ rs,
    const float* __restrict__ fcw, const float* __restrict__ V,
    float* __restrict__ uae, float* __restrict__ iae,
    float* __restrict__ linb, float* __restrict__ quadb)
{
  __shared__ __align__(16) float ivec[2*D_DIM];
  __shared__ float redw[8];
  __shared__ float qpart[10];
  const int b = blockIdx.x;
  const int tid = threadIdx.x, lane = tid & 63, wv = tid >> 6;

  if (tid < D_DIM) {
    int n = cnt[b]; n = n < SLOT_CAP ? n : SLOT_CAP;
    const int* cols = scol + (size_t)b*SLOT_CAP;
    const float* vals = sval + (size_t)b*SLOT_CAP;
    float acc = 0.f;
    for (int j = 0; j < n; ++j) acc += vals[j] * rs[(size_t)cols[j]*D_DIM + tid];
    ivec[tid] = acc;
    uae[(size_t)b*D_DIM + tid] = acc;
  } else if (tid >= 256 && tid < 256 + D_DIM) {
    const int t = tid - 256;
    int n = cnt[B_SZ + b]; n = n < SLOT_CAP ? n : SLOT_CAP;
    const int* cols = scol + (size_t)(B_SZ + b)*SLOT_CAP;
    const float* vals = sval + (size_t)(B_SZ + b)*SLOT_CAP;
    float acc = 0.f;
    for (int j = 0; j < n; ++j) acc += vals[j] * rs[(size_t)cols[j]*D_DIM + t];
    ivec[D_DIM + t] = acc;
    iae[(size_t)b*D_DIM + t] = acc;
  }
  __syncthreads();

  float lv = 0.f;
  if (tid < 2*D_DIM) lv = ivec[tid] * fcw[tid];
  #pragma unroll
  for (int o = 32; o > 0; o >>= 1) lv += __shfl_xor(lv, o);
  if (lane == 0) redw[wv] = lv;

  {
    const int k = wv;
    float s1 = 0.f, s2 = 0.f;
    for (int f = lane; f < 2*D_DIM; f += 64) {
      const float x = ivec[f];
      const float vk = V[f*10 + k];
      s1 += x*vk; s2 += x*x*vk*vk;
    }
    #pragma unroll
    for (int o = 32; o > 0; o >>= 1) { s1 += __shfl_xor(s1,o); s2 += __shfl_xor(s2,o); }
    if (lane == 0) qpart[k] = s1*s1 - s2;
  }
  if (wv < 2) {
    const int k = 8 + wv;
    float s1 = 0.f, s2 = 0.f;
    for (int f = lane; f < 2*D_DIM; f += 64) {
      const float x = ivec[f];
      const float vk = V[f*10 + k];
      s1 += x*vk; s2 += x*x*vk*vk;
    }
    #pragma unroll
    for (int o = 32; o > 0; o >>= 1) { s1 += __shfl_xor(s1,o); s2 += __shfl_xor(s2,o); }
    if (lane == 0) qpart[k] = s1*s1 - s2;
  }
  __syncthreads();
  if (tid == 0) {
    float lin = 0.f;
    #pragma unroll
    for (int i = 0; i < 8; ++i) lin += redw[i];
    float q = 0.f;
    #pragma unroll
    for (int i = 0; i < 10; ++i) q += qpart[i];
    linb[b] = lin; quadb[b] = q;
  }
}

// ---------------- K5: fused quad-reduce + prediction + all final scalars ----------------
__global__ __launch_bounds__(1024) void k_final2(
    const float* __restrict__ quadb, const float* __restrict__ linb,
    const float* __restrict__ fcb, const int* __restrict__ user,
    const int* __restrict__ item, const float* __restrict__ busers,
    const float* __restrict__ bitems, const float* __restrict__ label,
    const float* __restrict__ Wt, const float* __restrict__ abae,
    float* __restrict__ pred, float* __restrict__ rl, float* __restrict__ obj)
{
  __shared__ float sA[16], sB[16], sC[16];
  __shared__ float cninv[A_DIM];
  __shared__ float quad_s;
  const int tid = threadIdx.x;
  const int lane = tid & 63;
  const int wv = tid >> 6;

  float q = quadb[tid];
  #pragma unroll
  for (int o = 32; o > 0; o >>= 1) q += __shfl_xor(q, o);
  if (lane == 0) sA[wv] = q;

  if (tid < A_DIM) {
    float s = 0.f;
    for (int d = 0; d < D_DIM; ++d) { const float w = Wt[d*A_DIM + tid]; s += w*w; }
    cninv[tid] = 1.0f / fmaxf(sqrtf(s), EPS_);
  }
  __syncthreads();
  if (wv == 0) {
    float s = (lane < 16) ? sA[lane] : 0.f;
    #pragma unroll
    for (int o = 32; o > 0; o >>= 1) s += __shfl_xor(s, o);
    if (lane == 0) quad_s = s;
  }
  __syncthreads();

  const float p = 0.5f*quad_s + linb[tid] + fcb[0]
                + busers[user[tid]] + bitems[item[tid]];
  pred[tid] = p;
  const float dd = p - label[tid];
  const float myrl = dd*dd;
  rl[tid] = myrl;

  float u = 0.f;
  if (tid < 400) {
    const int a = tid / 20, c = tid % 20;
    float dot = 0.f;
    for (int d = 0; d < D_DIM; ++d) dot += Wt[d*A_DIM + a]*Wt[d*A_DIM + c];
    const float g = dot*cninv[a]*cninv[c] - (a==c ? 1.0f : 0.0f);
    u = g*g;
  }
  float js = 0.f;
  #pragma unroll
  for (int j = 0; j < 8; ++j) js += abae[tid + 1024*j];
  float ms = myrl;

  #pragma unroll
  for (int o = 32; o > 0; o >>= 1) {
    u += __shfl_xor(u,o); js += __shfl_xor(js,o); ms += __shfl_xor(ms,o);
  }
  if (lane == 0) { sA[wv] = u; sB[wv] = js; sC[wv] = ms; }
  __syncthreads();
  if (tid == 0) {
    float U = 0.f, J = 0.f, Ms = 0.f;
    for (int i = 0; i < 16; ++i) { U += sA[i]; J += sB[i]; Ms += sC[i]; }
    obj[0] = Ms/1024.0f + 0.01f*(J/8192.0f) + 0.01f*(U/400.0f);
  }
}

extern "C" void kernel_launch(void* const* d_in, const int* in_sizes, int n_in,
                              void* d_out, int out_size, void* d_ws, size_t ws_size,
                              hipStream_t stream) {
  const int*   hist   = (const int*)  d_in[0];
  const int*   neg    = (const int*)  d_in[1];
  const int*   user   = (const int*)  d_in[2];
  const int*   item   = (const int*)  d_in[3];
  const float* label  = (const float*)d_in[4];
  const int*   uidx   = (const int*)  d_in[5];
  const float* uval   = (const float*)d_in[6];
  const int*   iidx   = (const int*)  d_in[7];
  const float* ival   = (const float*)d_in[8];
  const float* emb    = (const float*)d_in[9];
  const float* Wm     = (const float*)d_in[10];
  const float* Ww     = (const float*)d_in[11];
  const float* bw     = (const float*)d_in[12];
  const float* Wt     = (const float*)d_in[13];
  const float* fcw    = (const float*)d_in[14];
  const float* fcb    = (const float*)d_in[15];
  const float* V      = (const float*)d_in[16];
  const float* busers = (const float*)d_in[17];
  const float* bitems = (const float*)d_in[18];

  float* out  = (float*)d_out;
  float* obj  = out;                       // 1
  float* rl   = out + 1;                   // 1024
  float* abae = out + 1 + B_SZ;            // 8192
  float* pred = out + 1 + B_SZ + RN_TOT;   // 1024
  float* uae  = pred + B_SZ;               // 204800
  float* iae  = uae + (size_t)B_SZ*D_DIM;  // 204800

  float* ws     = (float*)d_ws;
  float* rs     = ws;                              // R*D
  float* ys_all = rs + (size_t)R_TOT*D_DIM;        // R*D
  float* zn_all = ys_all + (size_t)R_TOT*D_DIM;    // RN*D
  float* vv_all = zn_all + (size_t)RN_TOT*D_DIM;   // R*D
  float* linb   = vv_all + (size_t)R_TOT*D_DIM;    // B
  float* quadb  = linb + B_SZ;                     // B
  float* sval   = quadb + B_SZ;                    // 2*B*SLOT_CAP floats
  int*   scol   = (int*)(sval + (size_t)2*B_SZ*SLOT_CAP);   // 2*B*SLOT_CAP ints
  int*   cnt    = scol + (size_t)2*B_SZ*SLOT_CAP;           // 2*B ints
  ushort* emb_h = (ushort*)(cnt + 2*B_SZ);                  // VOCAB*D halves

  const int cast_blocks = (VOCAB_C*D_DIM/4 + 255)/256;      // 6250

  k_cast  <<<cast_blocks, 256, 0, stream>>>(emb, emb_h, cnt);
  k_means2<<<S_TOT + NBUCK_BLK, 256, 0, stream>>>(hist, neg, emb_h,
                                                  ys_all, zn_all,
                                                  uidx, uval, iidx, ival,
                                                  cnt, scol, sval);
  k_matvec<<<R_TOT/KB_RT, 256, 0, stream>>>(ys_all, Wm, vv_all);
  k_attn  <<<R_TOT, 512, 0, stream>>>(hist, emb_h, vv_all, Ww, bw, Wt,
                                      zn_all, rs, abae);
  k_aggfm <<<B_SZ, 512, 0, stream>>>(cnt, scol, sval, rs, fcw, V,
                                     uae, iae, linb, quadb);
  k_final2<<<1, 1024, 0, stream>>>(quadb, linb, fcb, user, item, busers, bitems,
                                   label, Wt, abae, pred, rl, obj);
}

// Round 7
// 297.098 us; speedup vs baseline: 2.1221x; 1.0407x over previous
//
#include <hip/hip_runtime.h>
#include <hip/hip_fp16.h>
#include <math.h>

// Problem constants (match reference)
#define R_TOT 4096
#define L_LEN 128
#define D_DIM 200
#define A_DIM 20
#define NEGK  2
#define B_SZ  1024
#define NNZ_C 20480
#define RN_TOT (R_TOT*NEGK)
#define S_TOT (R_TOT + RN_TOT)
#define VOCAB_C 32000
#define EPS_ 1e-12f
#define SLOT_CAP 64          // Poisson(20) max bin ~45; 64 is safe
#define NBUCK_BLK 160        // 160*256 = 40960 = 2*NNZ_C

__device__ __forceinline__ float4 unpack4(const uint2 u) {
  union { unsigned v; __half2 h; } c0, c1;
  c0.v = u.x; c1.v = u.y;
  const float2 f0 = __half22float2(c0.h);
  const float2 f1 = __half22float2(c1.h);
  return make_float4(f0.x, f0.y, f1.x, f1.y);
}

__device__ __forceinline__ float dot8h(const uint4 q, const float4 va, const float4 vb) {
  const float4 e0 = unpack4(make_uint2(q.x, q.y));
  const float4 e1 = unpack4(make_uint2(q.z, q.w));
  return e0.x*va.x + e0.y*va.y + e0.z*va.z + e0.w*va.w
       + e1.x*vb.x + e1.y*vb.y + e1.z*vb.z + e1.w*vb.w;
}

// ---- DPP wave reductions (VALU pipe, zero DS-pipe traffic) ----
// Canonical GCN sequence (rocPRIM warp_reduce_dpp): row_shr:1/2/4/8 accumulate into
// lane 15 of each row; row_bcast15 (rmask 0xa) -> lane 31 = lanes 0-31 sum;
// row_bcast31 (rmask 0xc) -> lane 63 = full wave. R6 bug: used row_shl (wrong direction).
#define DPPI(old_, src_, ctrl, rmask) \
  __builtin_amdgcn_update_dpp(old_, src_, ctrl, rmask, 0xf, false)

__device__ __forceinline__ float dpp_sum32(float s) {   // lanes 31 & 63 hold half-wave sums
  s += __int_as_float(DPPI(0, __float_as_int(s), 0x111, 0xf));   // row_shr:1
  s += __int_as_float(DPPI(0, __float_as_int(s), 0x112, 0xf));   // row_shr:2
  s += __int_as_float(DPPI(0, __float_as_int(s), 0x114, 0xf));   // row_shr:4
  s += __int_as_float(DPPI(0, __float_as_int(s), 0x118, 0xf));   // row_shr:8
  s += __int_as_float(DPPI(0, __float_as_int(s), 0x142, 0xa));   // row_bcast15
  return s;
}
__device__ __forceinline__ float dpp_sum64(float s) {   // lane 63 holds wave sum
  s = dpp_sum32(s);
  s += __int_as_float(DPPI(0, __float_as_int(s), 0x143, 0xc));   // row_bcast31
  return s;
}
__device__ __forceinline__ float dpp_max64(float s) {   // lane 63 holds wave max
  s = fmaxf(s, __int_as_float(DPPI(__float_as_int(s), __float_as_int(s), 0x111, 0xf)));
  s = fmaxf(s, __int_as_float(DPPI(__float_as_int(s), __float_as_int(s), 0x112, 0xf)));
  s = fmaxf(s, __int_as_float(DPPI(__float_as_int(s), __float_as_int(s), 0x114, 0xf)));
  s = fmaxf(s, __int_as_float(DPPI(__float_as_int(s), __float_as_int(s), 0x118, 0xf)));
  s = fmaxf(s, __int_as_float(DPPI(__float_as_int(s), __float_as_int(s), 0x142, 0xa)));
  s = fmaxf(s, __int_as_float(DPPI(__float_as_int(s), __float_as_int(s), 0x143, 0xc)));
  return s;
}

// ---------------- K0: cast emb -> fp16 table; block 0 also zeroes bucket counters ----------------
__global__ __launch_bounds__(256) void k_cast(
    const float* __restrict__ emb, ushort* __restrict__ emb_h, int* __restrict__ cnt)
{
  if (blockIdx.x == 0) {
    for (int i = threadIdx.x; i < 2*B_SZ; i += 256) cnt[i] = 0;
  }
  const int idx = blockIdx.x*256 + threadIdx.x;
  if (idx < (VOCAB_C*D_DIM)/4) {
    const float4 v = reinterpret_cast<const float4*>(emb)[idx];
    ushort4 o;
    o.x = __half_as_ushort(__float2half(v.x));
    o.y = __half_as_ushort(__float2half(v.y));
    o.z = __half_as_ushort(__float2half(v.z));
    o.w = __half_as_ushort(__float2half(v.w));
    reinterpret_cast<ushort4*>(emb_h)[idx] = o;
  }
}

// ---------------- K1: combined means (pos+neg) + bucket tail ----------------
// 8-deep independent uint4 gathers per thread.
#define ACC8(Q) { \
  const float4 e0_ = unpack4(make_uint2((Q).x,(Q).y)); \
  const float4 e1_ = unpack4(make_uint2((Q).z,(Q).w)); \
  sA.x+=e0_.x; sA.y+=e0_.y; sA.z+=e0_.z; sA.w+=e0_.w; \
  sB.x+=e1_.x; sB.y+=e1_.y; sB.z+=e1_.z; sB.w+=e1_.w; }

__global__ __launch_bounds__(256, 8) void k_means2(
    const int* __restrict__ hist, const int* __restrict__ neg,
    const ushort* __restrict__ emb_h,
    float* __restrict__ ys_all, float* __restrict__ zn_all,
    const int* __restrict__ uidx, const float* __restrict__ uval,
    const int* __restrict__ iidx, const float* __restrict__ ival,
    int* __restrict__ cnt, int* __restrict__ scol, float* __restrict__ sval)
{
  const int sb = blockIdx.x;
  const int tid = threadIdx.x;

  if (sb >= S_TOT) {
    const int g = (sb - S_TOT)*256 + tid;
    if (g < NNZ_C) {
      const int b = uidx[g];
      const int slot = atomicAdd(&cnt[b], 1);
      if (slot < SLOT_CAP) {
        scol[b*SLOT_CAP + slot] = uidx[NNZ_C + g];
        sval[b*SLOT_CAP + slot] = uval[g];
      }
    } else {
      const int g2 = g - NNZ_C;
      const int b = iidx[g2];
      const int slot = atomicAdd(&cnt[B_SZ + b], 1);
      if (slot < SLOT_CAP) {
        scol[(B_SZ + b)*SLOT_CAP + slot] = iidx[NNZ_C + g2];
        sval[(B_SZ + b)*SLOT_CAP + slot] = ival[g2];
      }
    }
    return;
  }

  __shared__ int widx[L_LEN];
  __shared__ __align__(16) float part[8][D_DIM];
  const bool is_pos = (sb < R_TOT);
  const int* src = is_pos ? (hist + (size_t)sb*L_LEN)
                          : (neg + (size_t)(sb - R_TOT)*L_LEN);
  if (tid < L_LEN) widx[tid] = src[tid];
  __syncthreads();

  const int c5 = tid & 31;       // column chunk (active if < 25)
  const int j  = tid >> 5;       // 0..7 row group
  float4 sA = {0.f,0.f,0.f,0.f}, sB = {0.f,0.f,0.f,0.f};
  if (c5 < 25) {
    const size_t coff = 8*c5;
    uint4 q0 = *reinterpret_cast<const uint4*>(emb_h + (size_t)widx[j +   0]*D_DIM + coff);
    uint4 q1 = *reinterpret_cast<const uint4*>(emb_h + (size_t)widx[j +   8]*D_DIM + coff);
    uint4 q2 = *reinterpret_cast<const uint4*>(emb_h + (size_t)widx[j +  16]*D_DIM + coff);
    uint4 q3 = *reinterpret_cast<const uint4*>(emb_h + (size_t)widx[j +  24]*D_DIM + coff);
    uint4 q4 = *reinterpret_cast<const uint4*>(emb_h + (size_t)widx[j +  32]*D_DIM + coff);
    uint4 q5 = *reinterpret_cast<const uint4*>(emb_h + (size_t)widx[j +  40]*D_DIM + coff);
    uint4 q6 = *reinterpret_cast<const uint4*>(emb_h + (size_t)widx[j +  48]*D_DIM + coff);
    uint4 q7 = *reinterpret_cast<const uint4*>(emb_h + (size_t)widx[j +  56]*D_DIM + coff);
    ACC8(q0) ACC8(q1) ACC8(q2) ACC8(q3) ACC8(q4) ACC8(q5) ACC8(q6) ACC8(q7)
    q0 = *reinterpret_cast<const uint4*>(emb_h + (size_t)widx[j +  64]*D_DIM + coff);
    q1 = *reinterpret_cast<const uint4*>(emb_h + (size_t)widx[j +  72]*D_DIM + coff);
    q2 = *reinterpret_cast<const uint4*>(emb_h + (size_t)widx[j +  80]*D_DIM + coff);
    q3 = *reinterpret_cast<const uint4*>(emb_h + (size_t)widx[j +  88]*D_DIM + coff);
    q4 = *reinterpret_cast<const uint4*>(emb_h + (size_t)widx[j +  96]*D_DIM + coff);
    q5 = *reinterpret_cast<const uint4*>(emb_h + (size_t)widx[j + 104]*D_DIM + coff);
    q6 = *reinterpret_cast<const uint4*>(emb_h + (size_t)widx[j + 112]*D_DIM + coff);
    q7 = *reinterpret_cast<const uint4*>(emb_h + (size_t)widx[j + 120]*D_DIM + coff);
    ACC8(q0) ACC8(q1) ACC8(q2) ACC8(q3) ACC8(q4) ACC8(q5) ACC8(q6) ACC8(q7)
    *reinterpret_cast<float4*>(&part[j][8*c5])     = sA;
    *reinterpret_cast<float4*>(&part[j][8*c5 + 4]) = sB;
  }
  __syncthreads();
  float* dst = is_pos ? (ys_all + (size_t)sb*D_DIM)
                      : (zn_all + (size_t)(sb - R_TOT)*D_DIM);
  if (tid < D_DIM) {
    float a = 0.f;
    #pragma unroll
    for (int j2 = 0; j2 < 8; ++j2) a += part[j2][tid];
    dst[tid] = a * (1.0f/128.0f);
  }
}

// ---------------- K2: V = Y @ Wm (16 reviews/block) ----------------
#define KB_RT 16
__global__ __launch_bounds__(256, 2) void k_matvec(
    const float* __restrict__ ys_all, const float* __restrict__ Wm,
    float* __restrict__ vv_all)
{
  __shared__ float ysl[KB_RT][D_DIM];
  const int r0 = blockIdx.x * KB_RT;
  const int tid = threadIdx.x;
  for (int i = tid; i < KB_RT*D_DIM; i += 256)
    ysl[i / D_DIM][i % D_DIM] = ys_all[(size_t)r0*D_DIM + i];
  __syncthreads();
  if (tid < D_DIM) {
    float acc[KB_RT];
    #pragma unroll
    for (int r = 0; r < KB_RT; ++r) acc[r] = 0.f;
    #pragma unroll 4
    for (int k = 0; k < D_DIM; ++k) {
      const float w = Wm[k*D_DIM + tid];
      #pragma unroll
      for (int r = 0; r < KB_RT; ++r) acc[r] += ysl[r][k] * w;
    }
    #pragma unroll
    for (int r = 0; r < KB_RT; ++r)
      vv_all[(size_t)(r0 + r)*D_DIM + tid] = acc[r];
  }
}

// ---------------- K3: attn — register-resident tile, DPP reductions, ~15 KB LDS ----------------
// DS-pipe diagnosis (R5): ~170 DS ops/thread (shuffles+LDS tile) pinned k_attn at 82 µs.
// Gathers stay in q0..q7 REGISTERS, reused for z_s via flat-reshape algebra:
// chunk base X_k = 3200k + 8Y (Y=25j+c5); 3200 ≡ 0 mod 128 so ax offset l0=(8Y)&127 is
// k-invariant; output d_k = 25k + (Y>>4); slot = Y&15 -> 16 unique contributors per d.
// All reductions via DPP (VALU). LDS ~15 KB -> 3 blocks/CU at launch_bounds(512,6).
__global__ __launch_bounds__(512, 6) void k_attn(
    const int* __restrict__ hist, const ushort* __restrict__ emb_h,
    const float* __restrict__ vv_all,
    const float* __restrict__ Ww, const float* __restrict__ bw,
    const float* __restrict__ Wt, const float* __restrict__ zn_all,
    float* __restrict__ rs_out, float* __restrict__ abae)
{
  __shared__ __align__(16) float part[D_DIM][16];    // 12800 B z_s partials
  __shared__ __align__(16) float ax[L_LEN];          // 512 B
  __shared__ __align__(16) float zs[D_DIM];          // 800 B
  __shared__ __align__(16) float ubuf[240];          // widx (staging) / ptile+red
  int*   widx  = reinterpret_cast<int*>(ubuf);       // [0..128)
  float* ptile = ubuf;                               // [0..160)
  float* red   = ubuf + 160;                         // [160..240)

  const int r = blockIdx.x;
  const int tid = threadIdx.x, lane = tid & 63, wv = tid >> 6;
  const int c5 = tid & 31;      // column chunk (active if < 25)
  const int j  = tid >> 5;      // 0..15 row group
  const bool act = (c5 < 25);
  const int coff = 8*c5;

  if (tid < L_LEN) widx[tid] = hist[r*L_LEN + tid];
  float4 v8a = {0,0,0,0}, v8b = {0,0,0,0};
  if (act) {
    v8a = *reinterpret_cast<const float4*>(vv_all + (size_t)r*D_DIM + coff);
    v8b = *reinterpret_cast<const float4*>(vv_all + (size_t)r*D_DIM + coff + 4);
  }
  __syncthreads();                                   // B1

  // ---- gather (8 loads in flight, kept in regs) + zn prefetch + dx partials ----
  uint4 q0,q1,q2,q3,q4,q5,q6,q7;
  q0=q1=q2=q3=q4=q5=q6=q7=make_uint4(0,0,0,0);
  float zn0 = 0.f, zn1 = 0.f;
  float p0=0.f,p1=0.f,p2=0.f,p3=0.f,p4=0.f,p5=0.f,p6=0.f,p7=0.f;
  if (act) {
    q0 = *reinterpret_cast<const uint4*>(emb_h + (size_t)widx[j +   0]*D_DIM + coff);
    q1 = *reinterpret_cast<const uint4*>(emb_h + (size_t)widx[j +  16]*D_DIM + coff);
    q2 = *reinterpret_cast<const uint4*>(emb_h + (size_t)widx[j +  32]*D_DIM + coff);
    q3 = *reinterpret_cast<const uint4*>(emb_h + (size_t)widx[j +  48]*D_DIM + coff);
    q4 = *reinterpret_cast<const uint4*>(emb_h + (size_t)widx[j +  64]*D_DIM + coff);
    q5 = *reinterpret_cast<const uint4*>(emb_h + (size_t)widx[j +  80]*D_DIM + coff);
    q6 = *reinterpret_cast<const uint4*>(emb_h + (size_t)widx[j +  96]*D_DIM + coff);
    q7 = *reinterpret_cast<const uint4*>(emb_h + (size_t)widx[j + 112]*D_DIM + coff);
  }
  if (tid < D_DIM) {                 // independent; lands during serial phases
    zn0 = zn_all[(size_t)(2*r)*D_DIM + tid];
    zn1 = zn_all[(size_t)(2*r + 1)*D_DIM + tid];
  }
  if (act) {
    p0 = dot8h(q0, v8a, v8b); p1 = dot8h(q1, v8a, v8b);
    p2 = dot8h(q2, v8a, v8b); p3 = dot8h(q3, v8a, v8b);
    p4 = dot8h(q4, v8a, v8b); p5 = dot8h(q5, v8a, v8b);
    p6 = dot8h(q6, v8a, v8b); p7 = dot8h(q7, v8a, v8b);
  }
  // DPP half-wave sums (all lanes participate; inactive lanes contribute 0)
  p0 = dpp_sum32(p0); p1 = dpp_sum32(p1); p2 = dpp_sum32(p2); p3 = dpp_sum32(p3);
  p4 = dpp_sum32(p4); p5 = dpp_sum32(p5); p6 = dpp_sum32(p6); p7 = dpp_sum32(p7);
  if (c5 == 31) {                    // lanes 31 & 63 hold their half-wave's sums
    ax[j]      = p0; ax[j + 16]  = p1; ax[j + 32]  = p2; ax[j + 48]  = p3;
    ax[j + 64] = p4; ax[j + 80]  = p5; ax[j + 96]  = p6; ax[j + 112] = p7;
  }
  __syncthreads();                                   // B2 (widx dead after here)

  // ---- softmax max (wave 0, DPP) ----
  if (tid < 64) {
    float m = dpp_max64(fmaxf(ax[tid], ax[tid+64]));
    if (tid == 63) red[0] = m;
  }
  __syncthreads();                                   // B3
  // ---- exp + per-wave sum (waves 0,1; DPP) ----
  const float M = red[0];
  if (tid < L_LEN) {
    const float e = expf(ax[tid] - M);
    ax[tid] = e;
    const float s = dpp_sum64(e);
    if (lane == 63) red[1 + wv] = s;
  }
  __syncthreads();                                   // B4

  // ---- z_s partials from registers (flat-reshape algebra) ----
  if (act) {
    const int Y  = 25*j + c5;          // 0..399, unique per active thread
    const int l0 = (8*Y) & 127;        // ax offset, k-invariant
    const int v0 = Y >> 4;             // d_k = v0 + 25k
    const int sl = Y & 15;             // slot within output window
    const float4 ax8a = *reinterpret_cast<const float4*>(ax + l0);
    const float4 ax8b = *reinterpret_cast<const float4*>(ax + l0 + 4);
    part[v0 +   0][sl] = dot8h(q0, ax8a, ax8b);
    part[v0 +  25][sl] = dot8h(q1, ax8a, ax8b);
    part[v0 +  50][sl] = dot8h(q2, ax8a, ax8b);
    part[v0 +  75][sl] = dot8h(q3, ax8a, ax8b);
    part[v0 + 100][sl] = dot8h(q4, ax8a, ax8b);
    part[v0 + 125][sl] = dot8h(q5, ax8a, ax8b);
    part[v0 + 150][sl] = dot8h(q6, ax8a, ax8b);
    part[v0 + 175][sl] = dot8h(q7, ax8a, ax8b);
  }
  __syncthreads();                                   // B5

  // ---- zs[d] = Sinv * sum of 16 slot partials ----
  if (tid < D_DIM) {
    const float Sinv = 1.0f / (red[1] + red[2]);
    const float4 a0 = *reinterpret_cast<const float4*>(&part[tid][0]);
    const float4 a1 = *reinterpret_cast<const float4*>(&part[tid][4]);
    const float4 a2 = *reinterpret_cast<const float4*>(&part[tid][8]);
    const float4 a3 = *reinterpret_cast<const float4*>(&part[tid][12]);
    const float s = ((a0.x+a0.y)+(a0.z+a0.w)) + ((a1.x+a1.y)+(a1.z+a1.w))
                  + ((a2.x+a2.y)+(a2.z+a2.w)) + ((a3.x+a3.y)+(a3.z+a3.w));
    zs[tid] = s * Sinv;
  }
  __syncthreads();                                   // B6

  // ---- p_t[a] = z_s . Ww[a,:] + bw[a] — 8x20 partials ----
  if (tid < 160) {
    const int a = tid % 20, jj = tid / 20;
    float s = 0.f;
    #pragma unroll
    for (int ii = 0; ii < 25; ++ii) {
      const int d = jj + 8*ii;
      s += zs[d] * Ww[a*D_DIM + d];
    }
    ptile[tid] = s;
  }
  __syncthreads();                                   // B7
  if (tid < A_DIM) {
    float s = bw[tid];
    #pragma unroll
    for (int jj = 0; jj < 8; ++jj) s += ptile[jj*20 + tid];
    red[2 + tid] = s;
  }
  __syncthreads();                                   // B8

  // ---- r_s + fused norm partials (7 wave sums via DPP) ----
  float rsd = 0.f, zsd = 0.f;
  if (tid < D_DIM) {
    float acc = 0.f;
    #pragma unroll
    for (int a = 0; a < A_DIM; ++a) acc += red[2+a] * Wt[tid*A_DIM + a];
    rsd = acc; zsd = zs[tid];
    rs_out[(size_t)r*D_DIM + tid] = acc;
  } else { zn0 = 0.f; zn1 = 0.f; }
  float a0 = dpp_sum64(rsd*rsd), a1 = dpp_sum64(zsd*zsd), a2 = dpp_sum64(rsd*zsd);
  float b0 = dpp_sum64(zn0*zn0), b1 = dpp_sum64(zn0*rsd);
  float b2 = dpp_sum64(zn1*zn1), b3 = dpp_sum64(zn1*rsd);
  if (lane == 63) {
    red[22 + 0*8 + wv] = a0; red[22 + 1*8 + wv] = a1; red[22 + 2*8 + wv] = a2;
    red[22 + 3*8 + wv] = b0; red[22 + 4*8 + wv] = b1;
    red[22 + 5*8 + wv] = b2; red[22 + 6*8 + wv] = b3;
  }
  __syncthreads();                                   // B9

  // ---- parallel epilogue: 7 groups of 8 partials reduced by wave 0 ----
  if (tid < 64) {
    const int qi = tid >> 3, k = tid & 7;
    float v = (qi < 7) ? red[22 + 8*qi + k] : 0.f;
    v += __shfl_xor(v, 1); v += __shfl_xor(v, 2); v += __shfl_xor(v, 4);
    const float s0 = __shfl(v, 0),  s1 = __shfl(v, 8),  s2 = __shfl(v, 16);
    const float t0 = __shfl(v, 24), t1 = __shfl(v, 32);
    const float t2 = __shfl(v, 40), t3 = __shfl(v, 48);
    if (tid == 0) {
      const float nr = fmaxf(sqrtf(s0), EPS_);
      const float nz = fmaxf(sqrtf(s1), EPS_);
      const float c1 = s2 / (nr * nz);
      const float c2a = t1 / (fmaxf(sqrtf(t0), EPS_) * nr);
      const float c2b = t3 / (fmaxf(sqrtf(t2), EPS_) * nr);
      abae[2*r]     = fmaxf(c2a - c1 + 1.0f, 0.0f);
      abae[2*r + 1] = fmaxf(c2b - c1 + 1.0f, 0.0f);
    }
  }
}

// ---------------- K4: merged segment-sum apply + FM (one block per b) ----------------
__global__ __launch_bounds__(512) void k_aggfm(
    const int* __restrict__ cnt, const int* __restrict__ scol,
    const float* __restrict__ sval, const float* __restrict__ rs,
    const float* __restrict__ fcw, const float* __restrict__ V,
    float* __restrict__ uae, float* __restrict__ iae,
    float* __restrict__ linb, float* __restrict__ quadb)
{
  __shared__ __align__(16) float ivec[2*D_DIM];
  __shared__ float redw[8];
  __shared__ float qpart[10];
  const int b = blockIdx.x;
  const int tid = threadIdx.x, lane = tid & 63, wv = tid >> 6;

  if (tid < D_DIM) {
    int n = cnt[b]; n = n < SLOT_CAP ? n : SLOT_CAP;
    const int* cols = scol + (size_t)b*SLOT_CAP;
    const float* vals = sval + (size_t)b*SLOT_CAP;
    float acc = 0.f;
    for (int j = 0; j < n; ++j) acc += vals[j] * rs[(size_t)cols[j]*D_DIM + tid];
    ivec[tid] = acc;
    uae[(size_t)b*D_DIM + tid] = acc;
  } else if (tid >= 256 && tid < 256 + D_DIM) {
    const int t = tid - 256;
    int n = cnt[B_SZ + b]; n = n < SLOT_CAP ? n : SLOT_CAP;
    const int* cols = scol + (size_t)(B_SZ + b)*SLOT_CAP;
    const float* vals = sval + (size_t)(B_SZ + b)*SLOT_CAP;
    float acc = 0.f;
    for (int j = 0; j < n; ++j) acc += vals[j] * rs[(size_t)cols[j]*D_DIM + t];
    ivec[D_DIM + t] = acc;
    iae[(size_t)b*D_DIM + t] = acc;
  }
  __syncthreads();

  float lv = 0.f;
  if (tid < 2*D_DIM) lv = ivec[tid] * fcw[tid];
  #pragma unroll
  for (int o = 32; o > 0; o >>= 1) lv += __shfl_xor(lv, o);
  if (lane == 0) redw[wv] = lv;

  {
    const int k = wv;
    float s1 = 0.f, s2 = 0.f;
    for (int f = lane; f < 2*D_DIM; f += 64) {
      const float x = ivec[f];
      const float vk = V[f*10 + k];
      s1 += x*vk; s2 += x*x*vk*vk;
    }
    #pragma unroll
    for (int o = 32; o > 0; o >>= 1) { s1 += __shfl_xor(s1,o); s2 += __shfl_xor(s2,o); }
    if (lane == 0) qpart[k] = s1*s1 - s2;
  }
  if (wv < 2) {
    const int k = 8 + wv;
    float s1 = 0.f, s2 = 0.f;
    for (int f = lane; f < 2*D_DIM; f += 64) {
      const float x = ivec[f];
      const float vk = V[f*10 + k];
      s1 += x*vk; s2 += x*x*vk*vk;
    }
    #pragma unroll
    for (int o = 32; o > 0; o >>= 1) { s1 += __shfl_xor(s1,o); s2 += __shfl_xor(s2,o); }
    if (lane == 0) qpart[k] = s1*s1 - s2;
  }
  __syncthreads();
  if (tid == 0) {
    float lin = 0.f;
    #pragma unroll
    for (int i = 0; i < 8; ++i) lin += redw[i];
    float q = 0.f;
    #pragma unroll
    for (int i = 0; i < 10; ++i) q += qpart[i];
    linb[b] = lin; quadb[b] = q;
  }
}

// ---------------- K5: fused quad-reduce + prediction + all final scalars ----------------
__global__ __launch_bounds__(1024) void k_final2(
    const float* __restrict__ quadb, const float* __restrict__ linb,
    const float* __restrict__ fcb, const int* __restrict__ user,
    const int* __restrict__ item, const float* __restrict__ busers,
    const float* __restrict__ bitems, const float* __restrict__ label,
    const float* __restrict__ Wt, const float* __restrict__ abae,
    float* __restrict__ pred, float* __restrict__ rl, float* __restrict__ obj)
{
  __shared__ float sA[16], sB[16], sC[16];
  __shared__ float cninv[A_DIM];
  __shared__ float quad_s;
  const int tid = threadIdx.x;
  const int lane = tid & 63;
  const int wv = tid >> 6;

  float q = quadb[tid];
  #pragma unroll
  for (int o = 32; o > 0; o >>= 1) q += __shfl_xor(q, o);
  if (lane == 0) sA[wv] = q;

  if (tid < A_DIM) {
    float s = 0.f;
    for (int d = 0; d < D_DIM; ++d) { const float w = Wt[d*A_DIM + tid]; s += w*w; }
    cninv[tid] = 1.0f / fmaxf(sqrtf(s), EPS_);
  }
  __syncthreads();
  if (wv == 0) {
    float s = (lane < 16) ? sA[lane] : 0.f;
    #pragma unroll
    for (int o = 32; o > 0; o >>= 1) s += __shfl_xor(s, o);
    if (lane == 0) quad_s = s;
  }
  __syncthreads();

  const float p = 0.5f*quad_s + linb[tid] + fcb[0]
                + busers[user[tid]] + bitems[item[tid]];
  pred[tid] = p;
  const float dd = p - label[tid];
  const float myrl = dd*dd;
  rl[tid] = myrl;

  float u = 0.f;
  if (tid < 400) {
    const int a = tid / 20, c = tid % 20;
    float dot = 0.f;
    for (int d = 0; d < D_DIM; ++d) dot += Wt[d*A_DIM + a]*Wt[d*A_DIM + c];
    const float g = dot*cninv[a]*cninv[c] - (a==c ? 1.0f : 0.0f);
    u = g*g;
  }
  float js = 0.f;
  #pragma unroll
  for (int j = 0; j < 8; ++j) js += abae[tid + 1024*j];
  float ms = myrl;

  #pragma unroll
  for (int o = 32; o > 0; o >>= 1) {
    u += __shfl_xor(u,o); js += __shfl_xor(js,o); ms += __shfl_xor(ms,o);
  }
  if (lane == 0) { sA[wv] = u; sB[wv] = js; sC[wv] = ms; }
  __syncthreads();
  if (tid == 0) {
    float U = 0.f, J = 0.f, Ms = 0.f;
    for (int i = 0; i < 16; ++i) { U += sA[i]; J += sB[i]; Ms += sC[i]; }
    obj[0] = Ms/1024.0f + 0.01f*(J/8192.0f) + 0.01f*(U/400.0f);
  }
}

extern "C" void kernel_launch(void* const* d_in, const int* in_sizes, int n_in,
                              void* d_out, int out_size, void* d_ws, size_t ws_size,
                              hipStream_t stream) {
  const int*   hist   = (const int*)  d_in[0];
  const int*   neg    = (const int*)  d_in[1];
  const int*   user   = (const int*)  d_in[2];
  const int*   item   = (const int*)  d_in[3];
  const float* label  = (const float*)d_in[4];
  const int*   uidx   = (const int*)  d_in[5];
  const float* uval   = (const float*)d_in[6];
  const int*   iidx   = (const int*)  d_in[7];
  const float* ival   = (const float*)d_in[8];
  const float* emb    = (const float*)d_in[9];
  const float* Wm     = (const float*)d_in[10];
  const float* Ww     = (const float*)d_in[11];
  const float* bw     = (const float*)d_in[12];
  const float* Wt     = (const float*)d_in[13];
  const float* fcw    = (const float*)d_in[14];
  const float* fcb    = (const float*)d_in[15];
  const float* V      = (const float*)d_in[16];
  const float* busers = (const float*)d_in[17];
  const float* bitems = (const float*)d_in[18];

  float* out  = (float*)d_out;
  float* obj  = out;                       // 1
  float* rl   = out + 1;                   // 1024
  float* abae = out + 1 + B_SZ;            // 8192
  float* pred = out + 1 + B_SZ + RN_TOT;   // 1024
  float* uae  = pred + B_SZ;               // 204800
  float* iae  = uae + (size_t)B_SZ*D_DIM;  // 204800

  float* ws     = (float*)d_ws;
  float* rs     = ws;                              // R*D
  float* ys_all = rs + (size_t)R_TOT*D_DIM;        // R*D
  float* zn_all = ys_all + (size_t)R_TOT*D_DIM;    // RN*D
  float* vv_all = zn_all + (size_t)RN_TOT*D_DIM;   // R*D
  float* linb   = vv_all + (size_t)R_TOT*D_DIM;    // B
  float* quadb  = linb + B_SZ;                     // B
  float* sval   = quadb + B_SZ;                    // 2*B*SLOT_CAP floats
  int*   scol   = (int*)(sval + (size_t)2*B_SZ*SLOT_CAP);   // 2*B*SLOT_CAP ints
  int*   cnt    = scol + (size_t)2*B_SZ*SLOT_CAP;           // 2*B ints
  ushort* emb_h = (ushort*)(cnt + 2*B_SZ);                  // VOCAB*D halves

  const int cast_blocks = (VOCAB_C*D_DIM/4 + 255)/256;      // 6250

  k_cast  <<<cast_blocks, 256, 0, stream>>>(emb, emb_h, cnt);
  k_means2<<<S_TOT + NBUCK_BLK, 256, 0, stream>>>(hist, neg, emb_h,
                                                  ys_all, zn_all,
                                                  uidx, uval, iidx, ival,
                                                  cnt, scol, sval);
  k_matvec<<<R_TOT/KB_RT, 256, 0, stream>>>(ys_all, Wm, vv_all);
  k_attn  <<<R_TOT, 512, 0, stream>>>(hist, emb_h, vv_all, Ww, bw, Wt,
                                      zn_all, rs, abae);
  k_aggfm <<<B_SZ, 512, 0, stream>>>(cnt, scol, sval, rs, fcw, V,
                                     uae, iae, linb, quadb);
  k_final2<<<1, 1024, 0, stream>>>(quadb, linb, fcb, user, item, busers, bitems,
                                   label, Wt, abae, pred, rl, obj);
}

// Round 8
// 279.938 us; speedup vs baseline: 2.2522x; 1.0613x over previous
//
#include <hip/hip_runtime.h>
#include <hip/hip_fp16.h>
#include <math.h>

// Problem constants (match reference)
#define R_TOT 4096
#define L_LEN 128
#define D_DIM 200
#define A_DIM 20
#define NEGK  2
#define B_SZ  1024
#define NNZ_C 20480
#define RN_TOT (R_TOT*NEGK)
#define S_TOT (R_TOT + RN_TOT)
#define VOCAB_C 32000
#define VHALF 16000
#define EPS_ 1e-12f
#define SLOT_CAP 64          // Poisson(20) max bin ~45; 64 is safe
#define NBUCK_BLK 160        // 160*256 = 40960 = 2*NNZ_C

__device__ __forceinline__ float4 unpack4(const uint2 u) {
  union { unsigned v; __half2 h; } c0, c1;
  c0.v = u.x; c1.v = u.y;
  const float2 f0 = __half22float2(c0.h);
  const float2 f1 = __half22float2(c1.h);
  return make_float4(f0.x, f0.y, f1.x, f1.y);
}

__device__ __forceinline__ float dot8h(const uint4 q, const float4 va, const float4 vb) {
  const float4 e0 = unpack4(make_uint2(q.x, q.y));
  const float4 e1 = unpack4(make_uint2(q.z, q.w));
  return e0.x*va.x + e0.y*va.y + e0.z*va.z + e0.w*va.w
       + e1.x*vb.x + e1.y*vb.y + e1.z*vb.z + e1.w*vb.w;
}

// ---- DPP wave reductions (VALU pipe, zero DS-pipe traffic) ----
// rocPRIM sequence: row_shr:1/2/4/8 -> lane 15 of each row; row_bcast15 (0xa) ->
// lane 31 = lanes 0-31; row_bcast31 (0xc) -> lane 63 = full wave.
#define DPPI(old_, src_, ctrl, rmask) \
  __builtin_amdgcn_update_dpp(old_, src_, ctrl, rmask, 0xf, false)

__device__ __forceinline__ float dpp_sum32(float s) {   // lanes 31 & 63 hold half-wave sums
  s += __int_as_float(DPPI(0, __float_as_int(s), 0x111, 0xf));   // row_shr:1
  s += __int_as_float(DPPI(0, __float_as_int(s), 0x112, 0xf));   // row_shr:2
  s += __int_as_float(DPPI(0, __float_as_int(s), 0x114, 0xf));   // row_shr:4
  s += __int_as_float(DPPI(0, __float_as_int(s), 0x118, 0xf));   // row_shr:8
  s += __int_as_float(DPPI(0, __float_as_int(s), 0x142, 0xa));   // row_bcast15
  return s;
}
__device__ __forceinline__ float dpp_sum64(float s) {   // lane 63 holds wave sum
  s = dpp_sum32(s);
  s += __int_as_float(DPPI(0, __float_as_int(s), 0x143, 0xc));   // row_bcast31
  return s;
}
__device__ __forceinline__ float dpp_max64(float s) {   // lane 63 holds wave max
  s = fmaxf(s, __int_as_float(DPPI(__float_as_int(s), __float_as_int(s), 0x111, 0xf)));
  s = fmaxf(s, __int_as_float(DPPI(__float_as_int(s), __float_as_int(s), 0x112, 0xf)));
  s = fmaxf(s, __int_as_float(DPPI(__float_as_int(s), __float_as_int(s), 0x114, 0xf)));
  s = fmaxf(s, __int_as_float(DPPI(__float_as_int(s), __float_as_int(s), 0x118, 0xf)));
  s = fmaxf(s, __int_as_float(DPPI(__float_as_int(s), __float_as_int(s), 0x142, 0xa)));
  s = fmaxf(s, __int_as_float(DPPI(__float_as_int(s), __float_as_int(s), 0x143, 0xc)));
  return s;
}

// ---------------- K0: cast emb -> fp16 table; block 0 also zeroes bucket counters ----------------
__global__ __launch_bounds__(256) void k_cast(
    const float* __restrict__ emb, ushort* __restrict__ emb_h, int* __restrict__ cnt)
{
  if (blockIdx.x == 0) {
    for (int i = threadIdx.x; i < 2*B_SZ; i += 256) cnt[i] = 0;
  }
  const int idx = blockIdx.x*256 + threadIdx.x;
  if (idx < (VOCAB_C*D_DIM)/4) {
    const float4 v = reinterpret_cast<const float4*>(emb)[idx];
    ushort4 o;
    o.x = __half_as_ushort(__float2half(v.x));
    o.y = __half_as_ushort(__float2half(v.y));
    o.z = __half_as_ushort(__float2half(v.z));
    o.w = __half_as_ushort(__float2half(v.w));
    reinterpret_cast<ushort4*>(emb_h)[idx] = o;
  }
}

// ---------------- K1: means, vocab-range phased (2 launches) + bucket tail ----------------
// R7 diag: k_means2 @75.5µs is L2-capacity-miss bound (637 MB logical, 262 MB miss,
// 12.8 MB table vs 4 MB/XCD L2). Split gather into two global passes over vocab
// halves: per-pass working set 6.4 MB -> higher L2 hit. Out-of-range rows load row 0
// (L1-hot, free) and contribute via x0 FMA -> MLP and control flow unchanged.
// Phase A (lo=0): write raw partial sums; tail blocks build buckets.
// Phase B (lo=VHALF, finalize): add partial, scale by 1/128, write final.
#define ACC8M(Q, M) { \
  const float4 e0_ = unpack4(make_uint2((Q).x,(Q).y)); \
  const float4 e1_ = unpack4(make_uint2((Q).z,(Q).w)); \
  sA.x = fmaf(M, e0_.x, sA.x); sA.y = fmaf(M, e0_.y, sA.y); \
  sA.z = fmaf(M, e0_.z, sA.z); sA.w = fmaf(M, e0_.w, sA.w); \
  sB.x = fmaf(M, e1_.x, sB.x); sB.y = fmaf(M, e1_.y, sB.y); \
  sB.z = fmaf(M, e1_.z, sB.z); sB.w = fmaf(M, e1_.w, sB.w); }

__global__ __launch_bounds__(256, 8) void k_means_phase(
    const int* __restrict__ hist, const int* __restrict__ neg,
    const ushort* __restrict__ emb_h,
    float* __restrict__ ys_all, float* __restrict__ zn_all,
    const int* __restrict__ uidx, const float* __restrict__ uval,
    const int* __restrict__ iidx, const float* __restrict__ ival,
    int* __restrict__ cnt, int* __restrict__ scol, float* __restrict__ sval,
    int lo, int finalize)
{
  const int sb = blockIdx.x;
  const int tid = threadIdx.x;

  if (sb >= S_TOT) {            // bucket tail — phase A only (phase B grid = S_TOT)
    const int g = (sb - S_TOT)*256 + tid;
    if (g < NNZ_C) {
      const int b = uidx[g];
      const int slot = atomicAdd(&cnt[b], 1);
      if (slot < SLOT_CAP) {
        scol[b*SLOT_CAP + slot] = uidx[NNZ_C + g];
        sval[b*SLOT_CAP + slot] = uval[g];
      }
    } else {
      const int g2 = g - NNZ_C;
      const int b = iidx[g2];
      const int slot = atomicAdd(&cnt[B_SZ + b], 1);
      if (slot < SLOT_CAP) {
        scol[(B_SZ + b)*SLOT_CAP + slot] = iidx[NNZ_C + g2];
        sval[(B_SZ + b)*SLOT_CAP + slot] = ival[g2];
      }
    }
    return;
  }

  __shared__ int widx[L_LEN];
  __shared__ __align__(16) float part[8][D_DIM];
  const bool is_pos = (sb < R_TOT);
  const int* src = is_pos ? (hist + (size_t)sb*L_LEN)
                          : (neg + (size_t)(sb - R_TOT)*L_LEN);
  if (tid < L_LEN) widx[tid] = src[tid];
  __syncthreads();

  const int c5 = tid & 31;       // column chunk (active if < 25)
  const int j  = tid >> 5;       // 0..7 row group
  float4 sA = {0.f,0.f,0.f,0.f}, sB = {0.f,0.f,0.f,0.f};
  if (c5 < 25) {
    const size_t coff = 8*c5;
    #pragma unroll
    for (int half = 0; half < 2; ++half) {
      const int base = j + 64*half;
      int   wv_[8]; float m_[8];
      #pragma unroll
      for (int k = 0; k < 8; ++k) {
        const int w = widx[base + 8*k];
        const bool in = ((unsigned)(w - lo) < (unsigned)VHALF);
        wv_[k] = in ? w : 0;
        m_[k]  = in ? 1.f : 0.f;
      }
      const uint4 q0 = *reinterpret_cast<const uint4*>(emb_h + (size_t)wv_[0]*D_DIM + coff);
      const uint4 q1 = *reinterpret_cast<const uint4*>(emb_h + (size_t)wv_[1]*D_DIM + coff);
      const uint4 q2 = *reinterpret_cast<const uint4*>(emb_h + (size_t)wv_[2]*D_DIM + coff);
      const uint4 q3 = *reinterpret_cast<const uint4*>(emb_h + (size_t)wv_[3]*D_DIM + coff);
      const uint4 q4 = *reinterpret_cast<const uint4*>(emb_h + (size_t)wv_[4]*D_DIM + coff);
      const uint4 q5 = *reinterpret_cast<const uint4*>(emb_h + (size_t)wv_[5]*D_DIM + coff);
      const uint4 q6 = *reinterpret_cast<const uint4*>(emb_h + (size_t)wv_[6]*D_DIM + coff);
      const uint4 q7 = *reinterpret_cast<const uint4*>(emb_h + (size_t)wv_[7]*D_DIM + coff);
      ACC8M(q0, m_[0]) ACC8M(q1, m_[1]) ACC8M(q2, m_[2]) ACC8M(q3, m_[3])
      ACC8M(q4, m_[4]) ACC8M(q5, m_[5]) ACC8M(q6, m_[6]) ACC8M(q7, m_[7])
    }
    *reinterpret_cast<float4*>(&part[j][8*c5])     = sA;
    *reinterpret_cast<float4*>(&part[j][8*c5 + 4]) = sB;
  }
  __syncthreads();
  float* dst = is_pos ? (ys_all + (size_t)sb*D_DIM)
                      : (zn_all + (size_t)(sb - R_TOT)*D_DIM);
  if (tid < D_DIM) {
    float a = 0.f;
    #pragma unroll
    for (int j2 = 0; j2 < 8; ++j2) a += part[j2][tid];
    if (finalize) dst[tid] = (dst[tid] + a) * (1.0f/128.0f);
    else          dst[tid] = a;
  }
}

// ---------------- K2: V = Y @ Wm (16 reviews/block) ----------------
#define KB_RT 16
__global__ __launch_bounds__(256, 2) void k_matvec(
    const float* __restrict__ ys_all, const float* __restrict__ Wm,
    float* __restrict__ vv_all)
{
  __shared__ float ysl[KB_RT][D_DIM];
  const int r0 = blockIdx.x * KB_RT;
  const int tid = threadIdx.x;
  for (int i = tid; i < KB_RT*D_DIM; i += 256)
    ysl[i / D_DIM][i % D_DIM] = ys_all[(size_t)r0*D_DIM + i];
  __syncthreads();
  if (tid < D_DIM) {
    float acc[KB_RT];
    #pragma unroll
    for (int r = 0; r < KB_RT; ++r) acc[r] = 0.f;
    #pragma unroll 4
    for (int k = 0; k < D_DIM; ++k) {
      const float w = Wm[k*D_DIM + tid];
      #pragma unroll
      for (int r = 0; r < KB_RT; ++r) acc[r] += ysl[r][k] * w;
    }
    #pragma unroll
    for (int r = 0; r < KB_RT; ++r)
      vv_all[(size_t)(r0 + r)*D_DIM + tid] = acc[r];
  }
}

// ---------------- K3: attn — register-resident tile, DPP reductions, ~15 KB LDS ----------------
// (R7-verified.) Gathers stay in q0..q7 REGISTERS, reused for z_s via flat-reshape
// algebra: X_k = 3200k + 8Y (Y=25j+c5); l0=(8Y)&127 k-invariant; d_k = 25k + (Y>>4);
// slot = Y&15. All reductions via DPP (VALU).
__global__ __launch_bounds__(512, 6) void k_attn(
    const int* __restrict__ hist, const ushort* __restrict__ emb_h,
    const float* __restrict__ vv_all,
    const float* __restrict__ Ww, const float* __restrict__ bw,
    const float* __restrict__ Wt, const float* __restrict__ zn_all,
    float* __restrict__ rs_out, float* __restrict__ abae)
{
  __shared__ __align__(16) float part[D_DIM][16];    // 12800 B z_s partials
  __shared__ __align__(16) float ax[L_LEN];          // 512 B
  __shared__ __align__(16) float zs[D_DIM];          // 800 B
  __shared__ __align__(16) float ubuf[240];          // widx (staging) / ptile+red
  int*   widx  = reinterpret_cast<int*>(ubuf);       // [0..128)
  float* ptile = ubuf;                               // [0..160)
  float* red   = ubuf + 160;                         // [160..240)

  const int r = blockIdx.x;
  const int tid = threadIdx.x, lane = tid & 63, wv = tid >> 6;
  const int c5 = tid & 31;      // column chunk (active if < 25)
  const int j  = tid >> 5;      // 0..15 row group
  const bool act = (c5 < 25);
  const int coff = 8*c5;

  if (tid < L_LEN) widx[tid] = hist[r*L_LEN + tid];
  float4 v8a = {0,0,0,0}, v8b = {0,0,0,0};
  if (act) {
    v8a = *reinterpret_cast<const float4*>(vv_all + (size_t)r*D_DIM + coff);
    v8b = *reinterpret_cast<const float4*>(vv_all + (size_t)r*D_DIM + coff + 4);
  }
  __syncthreads();                                   // B1

  // ---- gather (8 loads in flight, kept in regs) + zn prefetch + dx partials ----
  uint4 q0,q1,q2,q3,q4,q5,q6,q7;
  q0=q1=q2=q3=q4=q5=q6=q7=make_uint4(0,0,0,0);
  float zn0 = 0.f, zn1 = 0.f;
  float p0=0.f,p1=0.f,p2=0.f,p3=0.f,p4=0.f,p5=0.f,p6=0.f,p7=0.f;
  if (act) {
    q0 = *reinterpret_cast<const uint4*>(emb_h + (size_t)widx[j +   0]*D_DIM + coff);
    q1 = *reinterpret_cast<const uint4*>(emb_h + (size_t)widx[j +  16]*D_DIM + coff);
    q2 = *reinterpret_cast<const uint4*>(emb_h + (size_t)widx[j +  32]*D_DIM + coff);
    q3 = *reinterpret_cast<const uint4*>(emb_h + (size_t)widx[j +  48]*D_DIM + coff);
    q4 = *reinterpret_cast<const uint4*>(emb_h + (size_t)widx[j +  64]*D_DIM + coff);
    q5 = *reinterpret_cast<const uint4*>(emb_h + (size_t)widx[j +  80]*D_DIM + coff);
    q6 = *reinterpret_cast<const uint4*>(emb_h + (size_t)widx[j +  96]*D_DIM + coff);
    q7 = *reinterpret_cast<const uint4*>(emb_h + (size_t)widx[j + 112]*D_DIM + coff);
  }
  if (tid < D_DIM) {                 // independent; lands during serial phases
    zn0 = zn_all[(size_t)(2*r)*D_DIM + tid];
    zn1 = zn_all[(size_t)(2*r + 1)*D_DIM + tid];
  }
  if (act) {
    p0 = dot8h(q0, v8a, v8b); p1 = dot8h(q1, v8a, v8b);
    p2 = dot8h(q2, v8a, v8b); p3 = dot8h(q3, v8a, v8b);
    p4 = dot8h(q4, v8a, v8b); p5 = dot8h(q5, v8a, v8b);
    p6 = dot8h(q6, v8a, v8b); p7 = dot8h(q7, v8a, v8b);
  }
  // DPP half-wave sums (all lanes participate; inactive lanes contribute 0)
  p0 = dpp_sum32(p0); p1 = dpp_sum32(p1); p2 = dpp_sum32(p2); p3 = dpp_sum32(p3);
  p4 = dpp_sum32(p4); p5 = dpp_sum32(p5); p6 = dpp_sum32(p6); p7 = dpp_sum32(p7);
  if (c5 == 31) {                    // lanes 31 & 63 hold their half-wave's sums
    ax[j]      = p0; ax[j + 16]  = p1; ax[j + 32]  = p2; ax[j + 48]  = p3;
    ax[j + 64] = p4; ax[j + 80]  = p5; ax[j + 96]  = p6; ax[j + 112] = p7;
  }
  __syncthreads();                                   // B2 (widx dead after here)

  // ---- softmax max (wave 0, DPP) ----
  if (tid < 64) {
    float m = dpp_max64(fmaxf(ax[tid], ax[tid+64]));
    if (tid == 63) red[0] = m;
  }
  __syncthreads();                                   // B3
  // ---- exp + per-wave sum (waves 0,1; DPP) ----
  const float M = red[0];
  if (tid < L_LEN) {
    const float e = expf(ax[tid] - M);
    ax[tid] = e;
    const float s = dpp_sum64(e);
    if (lane == 63) red[1 + wv] = s;
  }
  __syncthreads();                                   // B4

  // ---- z_s partials from registers (flat-reshape algebra) ----
  if (act) {
    const int Y  = 25*j + c5;          // 0..399, unique per active thread
    const int l0 = (8*Y) & 127;        // ax offset, k-invariant
    const int v0 = Y >> 4;             // d_k = v0 + 25k
    const int sl = Y & 15;             // slot within output window
    const float4 ax8a = *reinterpret_cast<const float4*>(ax + l0);
    const float4 ax8b = *reinterpret_cast<const float4*>(ax + l0 + 4);
    part[v0 +   0][sl] = dot8h(q0, ax8a, ax8b);
    part[v0 +  25][sl] = dot8h(q1, ax8a, ax8b);
    part[v0 +  50][sl] = dot8h(q2, ax8a, ax8b);
    part[v0 +  75][sl] = dot8h(q3, ax8a, ax8b);
    part[v0 + 100][sl] = dot8h(q4, ax8a, ax8b);
    part[v0 + 125][sl] = dot8h(q5, ax8a, ax8b);
    part[v0 + 150][sl] = dot8h(q6, ax8a, ax8b);
    part[v0 + 175][sl] = dot8h(q7, ax8a, ax8b);
  }
  __syncthreads();                                   // B5

  // ---- zs[d] = Sinv * sum of 16 slot partials ----
  if (tid < D_DIM) {
    const float Sinv = 1.0f / (red[1] + red[2]);
    const float4 a0 = *reinterpret_cast<const float4*>(&part[tid][0]);
    const float4 a1 = *reinterpret_cast<const float4*>(&part[tid][4]);
    const float4 a2 = *reinterpret_cast<const float4*>(&part[tid][8]);
    const float4 a3 = *reinterpret_cast<const float4*>(&part[tid][12]);
    const float s = ((a0.x+a0.y)+(a0.z+a0.w)) + ((a1.x+a1.y)+(a1.z+a1.w))
                  + ((a2.x+a2.y)+(a2.z+a2.w)) + ((a3.x+a3.y)+(a3.z+a3.w));
    zs[tid] = s * Sinv;
  }
  __syncthreads();                                   // B6

  // ---- p_t[a] = z_s . Ww[a,:] + bw[a] — 8x20 partials ----
  if (tid < 160) {
    const int a = tid % 20, jj = tid / 20;
    float s = 0.f;
    #pragma unroll
    for (int ii = 0; ii < 25; ++ii) {
      const int d = jj + 8*ii;
      s += zs[d] * Ww[a*D_DIM + d];
    }
    ptile[tid] = s;
  }
  __syncthreads();                                   // B7
  if (tid < A_DIM) {
    float s = bw[tid];
    #pragma unroll
    for (int jj = 0; jj < 8; ++jj) s += ptile[jj*20 + tid];
    red[2 + tid] = s;
  }
  __syncthreads();                                   // B8

  // ---- r_s + fused norm partials (7 wave sums via DPP) ----
  float rsd = 0.f, zsd = 0.f;
  if (tid < D_DIM) {
    float acc = 0.f;
    #pragma unroll
    for (int a = 0; a < A_DIM; ++a) acc += red[2+a] * Wt[tid*A_DIM + a];
    rsd = acc; zsd = zs[tid];
    rs_out[(size_t)r*D_DIM + tid] = acc;
  } else { zn0 = 0.f; zn1 = 0.f; }
  float a0 = dpp_sum64(rsd*rsd), a1 = dpp_sum64(zsd*zsd), a2 = dpp_sum64(rsd*zsd);
  float b0 = dpp_sum64(zn0*zn0), b1 = dpp_sum64(zn0*rsd);
  float b2 = dpp_sum64(zn1*zn1), b3 = dpp_sum64(zn1*rsd);
  if (lane == 63) {
    red[22 + 0*8 + wv] = a0; red[22 + 1*8 + wv] = a1; red[22 + 2*8 + wv] = a2;
    red[22 + 3*8 + wv] = b0; red[22 + 4*8 + wv] = b1;
    red[22 + 5*8 + wv] = b2; red[22 + 6*8 + wv] = b3;
  }
  __syncthreads();                                   // B9

  // ---- parallel epilogue: 7 groups of 8 partials reduced by wave 0 ----
  if (tid < 64) {
    const int qi = tid >> 3, k = tid & 7;
    float v = (qi < 7) ? red[22 + 8*qi + k] : 0.f;
    v += __shfl_xor(v, 1); v += __shfl_xor(v, 2); v += __shfl_xor(v, 4);
    const float s0 = __shfl(v, 0),  s1 = __shfl(v, 8),  s2 = __shfl(v, 16);
    const float t0 = __shfl(v, 24), t1 = __shfl(v, 32);
    const float t2 = __shfl(v, 40), t3 = __shfl(v, 48);
    if (tid == 0) {
      const float nr = fmaxf(sqrtf(s0), EPS_);
      const float nz = fmaxf(sqrtf(s1), EPS_);
      const float c1 = s2 / (nr * nz);
      const float c2a = t1 / (fmaxf(sqrtf(t0), EPS_) * nr);
      const float c2b = t3 / (fmaxf(sqrtf(t2), EPS_) * nr);
      abae[2*r]     = fmaxf(c2a - c1 + 1.0f, 0.0f);
      abae[2*r + 1] = fmaxf(c2b - c1 + 1.0f, 0.0f);
    }
  }
}

// ---------------- K4: merged segment-sum apply + FM + offloaded U/J (blocks B_SZ, B_SZ+1) ----------------
__global__ __launch_bounds__(512) void k_aggfm(
    const int* __restrict__ cnt, const int* __restrict__ scol,
    const float* __restrict__ sval, const float* __restrict__ rs,
    const float* __restrict__ fcw, const float* __restrict__ V,
    const float* __restrict__ Wt, const float* __restrict__ abae,
    float* __restrict__ uae, float* __restrict__ iae,
    float* __restrict__ linb, float* __restrict__ quadb,
    float* __restrict__ uj)
{
  __shared__ __align__(16) float ivec[2*D_DIM];
  __shared__ float redw[8];
  __shared__ float qpart[10];
  __shared__ float cninvS[A_DIM];
  const int b = blockIdx.x;
  const int tid = threadIdx.x, lane = tid & 63, wv = tid >> 6;

  if (b == B_SZ) {               // U_loss: Wt Gram (hidden under the 1024 agg blocks)
    if (tid < 400) {
      const int a = tid / 20, c = tid % 20;
      float dot = 0.f;
      #pragma unroll 4
      for (int d = 0; d < D_DIM; ++d) dot += Wt[d*A_DIM + a] * Wt[d*A_DIM + c];
      ivec[tid] = dot;
    }
    __syncthreads();
    if (tid < A_DIM) cninvS[tid] = 1.0f / fmaxf(sqrtf(ivec[tid*21]), EPS_);
    __syncthreads();
    float u = 0.f;
    if (tid < 400) {
      const int a = tid / 20, c = tid % 20;
      const float g = ivec[tid]*cninvS[a]*cninvS[c] - (a==c ? 1.0f : 0.0f);
      u = g*g;
    }
    #pragma unroll
    for (int o = 32; o > 0; o >>= 1) u += __shfl_xor(u, o);
    if (lane == 0) redw[wv] = u;
    __syncthreads();
    if (tid == 0) {
      float s = 0.f;
      #pragma unroll
      for (int i = 0; i < 8; ++i) s += redw[i];
      uj[0] = s;
    }
    return;
  }
  if (b == B_SZ + 1) {           // J: sum of abae
    float s = 0.f;
    for (int i = tid; i < RN_TOT; i += 512) s += abae[i];
    #pragma unroll
    for (int o = 32; o > 0; o >>= 1) s += __shfl_xor(s, o);
    if (lane == 0) redw[wv] = s;
    __syncthreads();
    if (tid == 0) {
      float t = 0.f;
      #pragma unroll
      for (int i = 0; i < 8; ++i) t += redw[i];
      uj[1] = t;
    }
    return;
  }

  if (tid < D_DIM) {
    int n = cnt[b]; n = n < SLOT_CAP ? n : SLOT_CAP;
    const int* cols = scol + (size_t)b*SLOT_CAP;
    const float* vals = sval + (size_t)b*SLOT_CAP;
    float acc = 0.f;
    for (int j = 0; j < n; ++j) acc += vals[j] * rs[(size_t)cols[j]*D_DIM + tid];
    ivec[tid] = acc;
    uae[(size_t)b*D_DIM + tid] = acc;
  } else if (tid >= 256 && tid < 256 + D_DIM) {
    const int t = tid - 256;
    int n = cnt[B_SZ + b]; n = n < SLOT_CAP ? n : SLOT_CAP;
    const int* cols = scol + (size_t)(B_SZ + b)*SLOT_CAP;
    const float* vals = sval + (size_t)(B_SZ + b)*SLOT_CAP;
    float acc = 0.f;
    for (int j = 0; j < n; ++j) acc += vals[j] * rs[(size_t)cols[j]*D_DIM + t];
    ivec[D_DIM + t] = acc;
    iae[(size_t)b*D_DIM + t] = acc;
  }
  __syncthreads();

  float lv = 0.f;
  if (tid < 2*D_DIM) lv = ivec[tid] * fcw[tid];
  #pragma unroll
  for (int o = 32; o > 0; o >>= 1) lv += __shfl_xor(lv, o);
  if (lane == 0) redw[wv] = lv;

  {
    const int k = wv;
    float s1 = 0.f, s2 = 0.f;
    for (int f = lane; f < 2*D_DIM; f += 64) {
      const float x = ivec[f];
      const float vk = V[f*10 + k];
      s1 += x*vk; s2 += x*x*vk*vk;
    }
    #pragma unroll
    for (int o = 32; o > 0; o >>= 1) { s1 += __shfl_xor(s1,o); s2 += __shfl_xor(s2,o); }
    if (lane == 0) qpart[k] = s1*s1 - s2;
  }
  if (wv < 2) {
    const int k = 8 + wv;
    float s1 = 0.f, s2 = 0.f;
    for (int f = lane; f < 2*D_DIM; f += 64) {
      const float x = ivec[f];
      const float vk = V[f*10 + k];
      s1 += x*vk; s2 += x*x*vk*vk;
    }
    #pragma unroll
    for (int o = 32; o > 0; o >>= 1) { s1 += __shfl_xor(s1,o); s2 += __shfl_xor(s2,o); }
    if (lane == 0) qpart[k] = s1*s1 - s2;
  }
  __syncthreads();
  if (tid == 0) {
    float lin = 0.f;
    #pragma unroll
    for (int i = 0; i < 8; ++i) lin += redw[i];
    float q = 0.f;
    #pragma unroll
    for (int i = 0; i < 10; ++i) q += qpart[i];
    linb[b] = lin; quadb[b] = q;
  }
}

// ---------------- K5: quad-reduce + prediction + final combine (U/J precomputed) ----------------
__global__ __launch_bounds__(1024) void k_final2(
    const float* __restrict__ quadb, const float* __restrict__ linb,
    const float* __restrict__ fcb, const int* __restrict__ user,
    const int* __restrict__ item, const float* __restrict__ busers,
    const float* __restrict__ bitems, const float* __restrict__ label,
    const float* __restrict__ uj,
    float* __restrict__ pred, float* __restrict__ rl, float* __restrict__ obj)
{
  __shared__ float sA[16], sC[16];
  __shared__ float quad_s;
  const int tid = threadIdx.x;
  const int lane = tid & 63;
  const int wv = tid >> 6;

  float q = quadb[tid];
  #pragma unroll
  for (int o = 32; o > 0; o >>= 1) q += __shfl_xor(q, o);
  if (lane == 0) sA[wv] = q;
  __syncthreads();
  if (wv == 0) {
    float s = (lane < 16) ? sA[lane] : 0.f;
    #pragma unroll
    for (int o = 32; o > 0; o >>= 1) s += __shfl_xor(s, o);
    if (lane == 0) quad_s = s;
  }
  __syncthreads();

  const float p = 0.5f*quad_s + linb[tid] + fcb[0]
                + busers[user[tid]] + bitems[item[tid]];
  pred[tid] = p;
  const float dd = p - label[tid];
  const float myrl = dd*dd;
  rl[tid] = myrl;

  float ms = myrl;
  #pragma unroll
  for (int o = 32; o > 0; o >>= 1) ms += __shfl_xor(ms, o);
  if (lane == 0) sC[wv] = ms;
  __syncthreads();
  if (tid == 0) {
    float Ms = 0.f;
    for (int i = 0; i < 16; ++i) Ms += sC[i];
    obj[0] = Ms/1024.0f + 0.01f*(uj[1]/8192.0f) + 0.01f*(uj[0]/400.0f);
  }
}

extern "C" void kernel_launch(void* const* d_in, const int* in_sizes, int n_in,
                              void* d_out, int out_size, void* d_ws, size_t ws_size,
                              hipStream_t stream) {
  const int*   hist   = (const int*)  d_in[0];
  const int*   neg    = (const int*)  d_in[1];
  const int*   user   = (const int*)  d_in[2];
  const int*   item   = (const int*)  d_in[3];
  const float* label  = (const float*)d_in[4];
  const int*   uidx   = (const int*)  d_in[5];
  const float* uval   = (const float*)d_in[6];
  const int*   iidx   = (const int*)  d_in[7];
  const float* ival   = (const float*)d_in[8];
  const float* emb    = (const float*)d_in[9];
  const float* Wm     = (const float*)d_in[10];
  const float* Ww     = (const float*)d_in[11];
  const float* bw     = (const float*)d_in[12];
  const float* Wt     = (const float*)d_in[13];
  const float* fcw    = (const float*)d_in[14];
  const float* fcb    = (const float*)d_in[15];
  const float* V      = (const float*)d_in[16];
  const float* busers = (const float*)d_in[17];
  const float* bitems = (const float*)d_in[18];

  float* out  = (float*)d_out;
  float* obj  = out;                       // 1
  float* rl   = out + 1;                   // 1024
  float* abae = out + 1 + B_SZ;            // 8192
  float* pred = out + 1 + B_SZ + RN_TOT;   // 1024
  float* uae  = pred + B_SZ;               // 204800
  float* iae  = uae + (size_t)B_SZ*D_DIM;  // 204800

  float* ws     = (float*)d_ws;
  float* rs     = ws;                              // R*D
  float* ys_all = rs + (size_t)R_TOT*D_DIM;        // R*D
  float* zn_all = ys_all + (size_t)R_TOT*D_DIM;    // RN*D
  float* vv_all = zn_all + (size_t)RN_TOT*D_DIM;   // R*D (reused as uj after k_attn)
  float* linb   = vv_all + (size_t)R_TOT*D_DIM;    // B
  float* quadb  = linb + B_SZ;                     // B
  float* sval   = quadb + B_SZ;                    // 2*B*SLOT_CAP floats
  int*   scol   = (int*)(sval + (size_t)2*B_SZ*SLOT_CAP);   // 2*B*SLOT_CAP ints
  int*   cnt    = scol + (size_t)2*B_SZ*SLOT_CAP;           // 2*B ints
  ushort* emb_h = (ushort*)(cnt + 2*B_SZ);                  // VOCAB*D halves
  float* uj     = vv_all;                          // [0]=U, [1]=J (vv dead post-attn)

  const int cast_blocks = (VOCAB_C*D_DIM/4 + 255)/256;      // 6250

  k_cast       <<<cast_blocks, 256, 0, stream>>>(emb, emb_h, cnt);
  k_means_phase<<<S_TOT + NBUCK_BLK, 256, 0, stream>>>(hist, neg, emb_h,
                                                       ys_all, zn_all,
                                                       uidx, uval, iidx, ival,
                                                       cnt, scol, sval, 0, 0);
  k_means_phase<<<S_TOT, 256, 0, stream>>>(hist, neg, emb_h,
                                           ys_all, zn_all,
                                           uidx, uval, iidx, ival,
                                           cnt, scol, sval, VHALF, 1);
  k_matvec     <<<R_TOT/KB_RT, 256, 0, stream>>>(ys_all, Wm, vv_all);
  k_attn       <<<R_TOT, 512, 0, stream>>>(hist, emb_h, vv_all, Ww, bw, Wt,
                                           zn_all, rs, abae);
  k_aggfm      <<<B_SZ + 2, 512, 0, stream>>>(cnt, scol, sval, rs, fcw, V, Wt, abae,
                                              uae, iae, linb, quadb, uj);
  k_final2     <<<1, 1024, 0, stream>>>(quadb, linb, fcb, user, item, busers, bitems,
                                        label, uj, pred, rl, obj);
}

// Round 9
// 276.237 us; speedup vs baseline: 2.2824x; 1.0134x over previous
//
#include <hip/hip_runtime.h>
#include <hip/hip_fp16.h>
#include <math.h>

// Problem constants (match reference)
#define R_TOT 4096
#define L_LEN 128
#define D_DIM 200
#define A_DIM 20
#define NEGK  2
#define B_SZ  1024
#define NNZ_C 20480
#define RN_TOT (R_TOT*NEGK)
#define S_TOT (R_TOT + RN_TOT)
#define VOCAB_C 32000
#define VHALF 16000
#define EPS_ 1e-12f
#define SLOT_CAP 64          // Poisson(20) max bin ~45; 64 is safe
#define NBUCK_BLK 160        // 160*256 = 40960 = 2*NNZ_C

__device__ __forceinline__ float4 unpack4(const uint2 u) {
  union { unsigned v; __half2 h; } c0, c1;
  c0.v = u.x; c1.v = u.y;
  const float2 f0 = __half22float2(c0.h);
  const float2 f1 = __half22float2(c1.h);
  return make_float4(f0.x, f0.y, f1.x, f1.y);
}

// ---- packed fp16 dot: v_dot2_f32_f16 (exact f32 products, f32 accumulate) ----
typedef _Float16 h2v __attribute__((ext_vector_type(2)));
__device__ __forceinline__ float fdot2u(unsigned a, unsigned b, float c) {
  union { unsigned u; h2v h; } ua, ub;
  ua.u = a; ub.u = b;
  return __builtin_amdgcn_fdot2(ua.h, ub.h, c, false);
}
__device__ __forceinline__ float dot8f(const uint4 q, const uint4 w, float c) {
  float s = c;
  s = fdot2u(q.x, w.x, s); s = fdot2u(q.y, w.y, s);
  s = fdot2u(q.z, w.z, s); s = fdot2u(q.w, w.w, s);
  return s;
}

// ---- DPP wave reductions (VALU pipe, zero DS-pipe traffic) ----
// rocPRIM sequence: row_shr:1/2/4/8 -> lane 15 of each row; row_bcast15 (0xa) ->
// lane 31 = lanes 0-31; row_bcast31 (0xc) -> lane 63 = full wave.
#define DPPI(old_, src_, ctrl, rmask) \
  __builtin_amdgcn_update_dpp(old_, src_, ctrl, rmask, 0xf, false)

__device__ __forceinline__ float dpp_sum32(float s) {   // lanes 31 & 63 hold half-wave sums
  s += __int_as_float(DPPI(0, __float_as_int(s), 0x111, 0xf));   // row_shr:1
  s += __int_as_float(DPPI(0, __float_as_int(s), 0x112, 0xf));   // row_shr:2
  s += __int_as_float(DPPI(0, __float_as_int(s), 0x114, 0xf));   // row_shr:4
  s += __int_as_float(DPPI(0, __float_as_int(s), 0x118, 0xf));   // row_shr:8
  s += __int_as_float(DPPI(0, __float_as_int(s), 0x142, 0xa));   // row_bcast15
  return s;
}
__device__ __forceinline__ float dpp_sum64(float s) {   // lane 63 holds wave sum
  s = dpp_sum32(s);
  s += __int_as_float(DPPI(0, __float_as_int(s), 0x143, 0xc));   // row_bcast31
  return s;
}
__device__ __forceinline__ float dpp_max64(float s) {   // lane 63 holds wave max
  s = fmaxf(s, __int_as_float(DPPI(__float_as_int(s), __float_as_int(s), 0x111, 0xf)));
  s = fmaxf(s, __int_as_float(DPPI(__float_as_int(s), __float_as_int(s), 0x112, 0xf)));
  s = fmaxf(s, __int_as_float(DPPI(__float_as_int(s), __float_as_int(s), 0x114, 0xf)));
  s = fmaxf(s, __int_as_float(DPPI(__float_as_int(s), __float_as_int(s), 0x118, 0xf)));
  s = fmaxf(s, __int_as_float(DPPI(__float_as_int(s), __float_as_int(s), 0x142, 0xa)));
  s = fmaxf(s, __int_as_float(DPPI(__float_as_int(s), __float_as_int(s), 0x143, 0xc)));
  return s;
}

// ---------------- K0: cast emb -> fp16 table; block 0 also zeroes bucket counters ----------------
__global__ __launch_bounds__(256) void k_cast(
    const float* __restrict__ emb, ushort* __restrict__ emb_h, int* __restrict__ cnt)
{
  if (blockIdx.x == 0) {
    for (int i = threadIdx.x; i < 2*B_SZ; i += 256) cnt[i] = 0;
  }
  const int idx = blockIdx.x*256 + threadIdx.x;
  if (idx < (VOCAB_C*D_DIM)/4) {
    const float4 v = reinterpret_cast<const float4*>(emb)[idx];
    ushort4 o;
    o.x = __half_as_ushort(__float2half(v.x));
    o.y = __half_as_ushort(__float2half(v.y));
    o.z = __half_as_ushort(__float2half(v.z));
    o.w = __half_as_ushort(__float2half(v.w));
    reinterpret_cast<ushort4*>(emb_h)[idx] = o;
  }
}

// ---------------- K1: means, vocab-range phased (2 launches) + bucket tail ----------------
// (R8-verified: per-pass working set 6.4 MB -> L2-resident; out-of-range rows load
// row 0, contribute via x0 FMA.)
#define ACC8M(Q, M) { \
  const float4 e0_ = unpack4(make_uint2((Q).x,(Q).y)); \
  const float4 e1_ = unpack4(make_uint2((Q).z,(Q).w)); \
  sA.x = fmaf(M, e0_.x, sA.x); sA.y = fmaf(M, e0_.y, sA.y); \
  sA.z = fmaf(M, e0_.z, sA.z); sA.w = fmaf(M, e0_.w, sA.w); \
  sB.x = fmaf(M, e1_.x, sB.x); sB.y = fmaf(M, e1_.y, sB.y); \
  sB.z = fmaf(M, e1_.z, sB.z); sB.w = fmaf(M, e1_.w, sB.w); }

__global__ __launch_bounds__(256, 8) void k_means_phase(
    const int* __restrict__ hist, const int* __restrict__ neg,
    const ushort* __restrict__ emb_h,
    float* __restrict__ ys_all, float* __restrict__ zn_all,
    const int* __restrict__ uidx, const float* __restrict__ uval,
    const int* __restrict__ iidx, const float* __restrict__ ival,
    int* __restrict__ cnt, int* __restrict__ scol, float* __restrict__ sval,
    int lo, int finalize)
{
  const int sb = blockIdx.x;
  const int tid = threadIdx.x;

  if (sb >= S_TOT) {            // bucket tail — phase A only (phase B grid = S_TOT)
    const int g = (sb - S_TOT)*256 + tid;
    if (g < NNZ_C) {
      const int b = uidx[g];
      const int slot = atomicAdd(&cnt[b], 1);
      if (slot < SLOT_CAP) {
        scol[b*SLOT_CAP + slot] = uidx[NNZ_C + g];
        sval[b*SLOT_CAP + slot] = uval[g];
      }
    } else {
      const int g2 = g - NNZ_C;
      const int b = iidx[g2];
      const int slot = atomicAdd(&cnt[B_SZ + b], 1);
      if (slot < SLOT_CAP) {
        scol[(B_SZ + b)*SLOT_CAP + slot] = iidx[NNZ_C + g2];
        sval[(B_SZ + b)*SLOT_CAP + slot] = ival[g2];
      }
    }
    return;
  }

  __shared__ int widx[L_LEN];
  __shared__ __align__(16) float part[8][D_DIM];
  const bool is_pos = (sb < R_TOT);
  const int* src = is_pos ? (hist + (size_t)sb*L_LEN)
                          : (neg + (size_t)(sb - R_TOT)*L_LEN);
  if (tid < L_LEN) widx[tid] = src[tid];
  __syncthreads();

  const int c5 = tid & 31;       // column chunk (active if < 25)
  const int j  = tid >> 5;       // 0..7 row group
  float4 sA = {0.f,0.f,0.f,0.f}, sB = {0.f,0.f,0.f,0.f};
  if (c5 < 25) {
    const size_t coff = 8*c5;
    #pragma unroll
    for (int half = 0; half < 2; ++half) {
      const int base = j + 64*half;
      int   wv_[8]; float m_[8];
      #pragma unroll
      for (int k = 0; k < 8; ++k) {
        const int w = widx[base + 8*k];
        const bool in = ((unsigned)(w - lo) < (unsigned)VHALF);
        wv_[k] = in ? w : 0;
        m_[k]  = in ? 1.f : 0.f;
      }
      const uint4 q0 = *reinterpret_cast<const uint4*>(emb_h + (size_t)wv_[0]*D_DIM + coff);
      const uint4 q1 = *reinterpret_cast<const uint4*>(emb_h + (size_t)wv_[1]*D_DIM + coff);
      const uint4 q2 = *reinterpret_cast<const uint4*>(emb_h + (size_t)wv_[2]*D_DIM + coff);
      const uint4 q3 = *reinterpret_cast<const uint4*>(emb_h + (size_t)wv_[3]*D_DIM + coff);
      const uint4 q4 = *reinterpret_cast<const uint4*>(emb_h + (size_t)wv_[4]*D_DIM + coff);
      const uint4 q5 = *reinterpret_cast<const uint4*>(emb_h + (size_t)wv_[5]*D_DIM + coff);
      const uint4 q6 = *reinterpret_cast<const uint4*>(emb_h + (size_t)wv_[6]*D_DIM + coff);
      const uint4 q7 = *reinterpret_cast<const uint4*>(emb_h + (size_t)wv_[7]*D_DIM + coff);
      ACC8M(q0, m_[0]) ACC8M(q1, m_[1]) ACC8M(q2, m_[2]) ACC8M(q3, m_[3])
      ACC8M(q4, m_[4]) ACC8M(q5, m_[5]) ACC8M(q6, m_[6]) ACC8M(q7, m_[7])
    }
    *reinterpret_cast<float4*>(&part[j][8*c5])     = sA;
    *reinterpret_cast<float4*>(&part[j][8*c5 + 4]) = sB;
  }
  __syncthreads();
  float* dst = is_pos ? (ys_all + (size_t)sb*D_DIM)
                      : (zn_all + (size_t)(sb - R_TOT)*D_DIM);
  if (tid < D_DIM) {
    float a = 0.f;
    #pragma unroll
    for (int j2 = 0; j2 < 8; ++j2) a += part[j2][tid];
    if (finalize) dst[tid] = (dst[tid] + a) * (1.0f/128.0f);
    else          dst[tid] = a;
  }
}

// ---------------- K2: V = Y @ Wm (16 reviews/block) — fp16 output for fdot2 ----------------
#define KB_RT 16
__global__ __launch_bounds__(256, 2) void k_matvec(
    const float* __restrict__ ys_all, const float* __restrict__ Wm,
    ushort* __restrict__ vvh)
{
  __shared__ float ysl[KB_RT][D_DIM];
  const int r0 = blockIdx.x * KB_RT;
  const int tid = threadIdx.x;
  for (int i = tid; i < KB_RT*D_DIM; i += 256)
    ysl[i / D_DIM][i % D_DIM] = ys_all[(size_t)r0*D_DIM + i];
  __syncthreads();
  if (tid < D_DIM) {
    float acc[KB_RT];
    #pragma unroll
    for (int r = 0; r < KB_RT; ++r) acc[r] = 0.f;
    #pragma unroll 4
    for (int k = 0; k < D_DIM; ++k) {
      const float w = Wm[k*D_DIM + tid];
      #pragma unroll
      for (int r = 0; r < KB_RT; ++r) acc[r] += ysl[r][k] * w;
    }
    #pragma unroll
    for (int r = 0; r < KB_RT; ++r)
      vvh[(size_t)(r0 + r)*D_DIM + tid] = __half_as_ushort(__float2half(acc[r]));
  }
}

// ---------------- K3: attn — register tile + DPP + packed v_dot2_f32_f16 ----------------
// (R7/R8-verified structure.) fdot2 cuts dx/z_s VALU ~4x: each 8-half dot = 4
// v_dot2_f32_f16 (exact f32 products) vs ~16 cvt+fma. vv read as fp16 (quantized,
// rel ~5e-4, |dx|~O(1) -> negligible); ax stored to LDS as fp16 for the z_s dot.
__global__ __launch_bounds__(512, 6) void k_attn(
    const int* __restrict__ hist, const ushort* __restrict__ emb_h,
    const ushort* __restrict__ vvh,
    const float* __restrict__ Ww, const float* __restrict__ bw,
    const float* __restrict__ Wt, const float* __restrict__ zn_all,
    float* __restrict__ rs_out, float* __restrict__ abae)
{
  __shared__ __align__(16) float part[D_DIM][16];    // 12800 B z_s partials
  __shared__ __align__(16) float ax[L_LEN];          // 512 B (dx, then exp f32)
  __shared__ __align__(16) ushort axh[L_LEN];        // 256 B (exp as fp16)
  __shared__ __align__(16) float zs[D_DIM];          // 800 B
  __shared__ __align__(16) float ubuf[240];          // widx (staging) / ptile+red
  int*   widx  = reinterpret_cast<int*>(ubuf);       // [0..128)
  float* ptile = ubuf;                               // [0..160)
  float* red   = ubuf + 160;                         // [160..240)

  const int r = blockIdx.x;
  const int tid = threadIdx.x, lane = tid & 63, wv = tid >> 6;
  const int c5 = tid & 31;      // column chunk (active if < 25)
  const int j  = tid >> 5;      // 0..15 row group
  const bool act = (c5 < 25);
  const int coff = 8*c5;

  if (tid < L_LEN) widx[tid] = hist[r*L_LEN + tid];
  uint4 v8u = make_uint4(0,0,0,0);
  if (act) v8u = *reinterpret_cast<const uint4*>(vvh + (size_t)r*D_DIM + coff);
  __syncthreads();                                   // B1

  // ---- gather (8 loads in flight, kept in regs) + zn prefetch + dx partials ----
  uint4 q0,q1,q2,q3,q4,q5,q6,q7;
  q0=q1=q2=q3=q4=q5=q6=q7=make_uint4(0,0,0,0);
  float zn0 = 0.f, zn1 = 0.f;
  float p0=0.f,p1=0.f,p2=0.f,p3=0.f,p4=0.f,p5=0.f,p6=0.f,p7=0.f;
  if (act) {
    q0 = *reinterpret_cast<const uint4*>(emb_h + (size_t)widx[j +   0]*D_DIM + coff);
    q1 = *reinterpret_cast<const uint4*>(emb_h + (size_t)widx[j +  16]*D_DIM + coff);
    q2 = *reinterpret_cast<const uint4*>(emb_h + (size_t)widx[j +  32]*D_DIM + coff);
    q3 = *reinterpret_cast<const uint4*>(emb_h + (size_t)widx[j +  48]*D_DIM + coff);
    q4 = *reinterpret_cast<const uint4*>(emb_h + (size_t)widx[j +  64]*D_DIM + coff);
    q5 = *reinterpret_cast<const uint4*>(emb_h + (size_t)widx[j +  80]*D_DIM + coff);
    q6 = *reinterpret_cast<const uint4*>(emb_h + (size_t)widx[j +  96]*D_DIM + coff);
    q7 = *reinterpret_cast<const uint4*>(emb_h + (size_t)widx[j + 112]*D_DIM + coff);
  }
  if (tid < D_DIM) {                 // independent; lands during serial phases
    zn0 = zn_all[(size_t)(2*r)*D_DIM + tid];
    zn1 = zn_all[(size_t)(2*r + 1)*D_DIM + tid];
  }
  if (act) {
    p0 = dot8f(q0, v8u, 0.f); p1 = dot8f(q1, v8u, 0.f);
    p2 = dot8f(q2, v8u, 0.f); p3 = dot8f(q3, v8u, 0.f);
    p4 = dot8f(q4, v8u, 0.f); p5 = dot8f(q5, v8u, 0.f);
    p6 = dot8f(q6, v8u, 0.f); p7 = dot8f(q7, v8u, 0.f);
  }
  // DPP half-wave sums (all lanes participate; inactive lanes contribute 0)
  p0 = dpp_sum32(p0); p1 = dpp_sum32(p1); p2 = dpp_sum32(p2); p3 = dpp_sum32(p3);
  p4 = dpp_sum32(p4); p5 = dpp_sum32(p5); p6 = dpp_sum32(p6); p7 = dpp_sum32(p7);
  if (c5 == 31) {                    // lanes 31 & 63 hold their half-wave's sums
    ax[j]      = p0; ax[j + 16]  = p1; ax[j + 32]  = p2; ax[j + 48]  = p3;
    ax[j + 64] = p4; ax[j + 80]  = p5; ax[j + 96]  = p6; ax[j + 112] = p7;
  }
  __syncthreads();                                   // B2 (widx dead after here)

  // ---- softmax max (wave 0, DPP) ----
  if (tid < 64) {
    float m = dpp_max64(fmaxf(ax[tid], ax[tid+64]));
    if (tid == 63) red[0] = m;
  }
  __syncthreads();                                   // B3
  // ---- exp + per-wave sum (waves 0,1; DPP); store fp16 copy for z_s dot ----
  const float M = red[0];
  if (tid < L_LEN) {
    const float e = expf(ax[tid] - M);
    axh[tid] = __half_as_ushort(__float2half(e));
    const float s = dpp_sum64(e);
    if (lane == 63) red[1 + wv] = s;
  }
  __syncthreads();                                   // B4

  // ---- z_s partials from registers (flat-reshape algebra, fdot2) ----
  if (act) {
    const int Y  = 25*j + c5;          // 0..399, unique per active thread
    const int l0 = (8*Y) & 127;        // axh offset, k-invariant (multiple of 8)
    const int v0 = Y >> 4;             // d_k = v0 + 25k
    const int sl = Y & 15;             // slot within output window
    const uint4 ax8u = *reinterpret_cast<const uint4*>(axh + l0);
    part[v0 +   0][sl] = dot8f(q0, ax8u, 0.f);
    part[v0 +  25][sl] = dot8f(q1, ax8u, 0.f);
    part[v0 +  50][sl] = dot8f(q2, ax8u, 0.f);
    part[v0 +  75][sl] = dot8f(q3, ax8u, 0.f);
    part[v0 + 100][sl] = dot8f(q4, ax8u, 0.f);
    part[v0 + 125][sl] = dot8f(q5, ax8u, 0.f);
    part[v0 + 150][sl] = dot8f(q6, ax8u, 0.f);
    part[v0 + 175][sl] = dot8f(q7, ax8u, 0.f);
  }
  __syncthreads();                                   // B5

  // ---- zs[d] = Sinv * sum of 16 slot partials ----
  if (tid < D_DIM) {
    const float Sinv = 1.0f / (red[1] + red[2]);
    const float4 a0 = *reinterpret_cast<const float4*>(&part[tid][0]);
    const float4 a1 = *reinterpret_cast<const float4*>(&part[tid][4]);
    const float4 a2 = *reinterpret_cast<const float4*>(&part[tid][8]);
    const float4 a3 = *reinterpret_cast<const float4*>(&part[tid][12]);
    const float s = ((a0.x+a0.y)+(a0.z+a0.w)) + ((a1.x+a1.y)+(a1.z+a1.w))
                  + ((a2.x+a2.y)+(a2.z+a2.w)) + ((a3.x+a3.y)+(a3.z+a3.w));
    zs[tid] = s * Sinv;
  }
  __syncthreads();                                   // B6

  // ---- p_t[a] = z_s . Ww[a,:] + bw[a] — 8x20 partials ----
  if (tid < 160) {
    const int a = tid % 20, jj = tid / 20;
    float s = 0.f;
    #pragma unroll
    for (int ii = 0; ii < 25; ++ii) {
      const int d = jj + 8*ii;
      s += zs[d] * Ww[a*D_DIM + d];
    }
    ptile[tid] = s;
  }
  __syncthreads();                                   // B7
  if (tid < A_DIM) {
    float s = bw[tid];
    #pragma unroll
    for (int jj = 0; jj < 8; ++jj) s += ptile[jj*20 + tid];
    red[2 + tid] = s;
  }
  __syncthreads();                                   // B8

  // ---- r_s + fused norm partials (7 wave sums via DPP) ----
  float rsd = 0.f, zsd = 0.f;
  if (tid < D_DIM) {
    float acc = 0.f;
    #pragma unroll
    for (int a = 0; a < A_DIM; ++a) acc += red[2+a] * Wt[tid*A_DIM + a];
    rsd = acc; zsd = zs[tid];
    rs_out[(size_t)r*D_DIM + tid] = acc;
  } else { zn0 = 0.f; zn1 = 0.f; }
  float a0 = dpp_sum64(rsd*rsd), a1 = dpp_sum64(zsd*zsd), a2 = dpp_sum64(rsd*zsd);
  float b0 = dpp_sum64(zn0*zn0), b1 = dpp_sum64(zn0*rsd);
  float b2 = dpp_sum64(zn1*zn1), b3 = dpp_sum64(zn1*rsd);
  if (lane == 63) {
    red[22 + 0*8 + wv] = a0; red[22 + 1*8 + wv] = a1; red[22 + 2*8 + wv] = a2;
    red[22 + 3*8 + wv] = b0; red[22 + 4*8 + wv] = b1;
    red[22 + 5*8 + wv] = b2; red[22 + 6*8 + wv] = b3;
  }
  __syncthreads();                                   // B9

  // ---- parallel epilogue: 7 groups of 8 partials reduced by wave 0 ----
  if (tid < 64) {
    const int qi = tid >> 3, k = tid & 7;
    float v = (qi < 7) ? red[22 + 8*qi + k] : 0.f;
    v += __shfl_xor(v, 1); v += __shfl_xor(v, 2); v += __shfl_xor(v, 4);
    const float s0 = __shfl(v, 0),  s1 = __shfl(v, 8),  s2 = __shfl(v, 16);
    const float t0 = __shfl(v, 24), t1 = __shfl(v, 32);
    const float t2 = __shfl(v, 40), t3 = __shfl(v, 48);
    if (tid == 0) {
      const float nr = fmaxf(sqrtf(s0), EPS_);
      const float nz = fmaxf(sqrtf(s1), EPS_);
      const float c1 = s2 / (nr * nz);
      const float c2a = t1 / (fmaxf(sqrtf(t0), EPS_) * nr);
      const float c2b = t3 / (fmaxf(sqrtf(t2), EPS_) * nr);
      abae[2*r]     = fmaxf(c2a - c1 + 1.0f, 0.0f);
      abae[2*r + 1] = fmaxf(c2b - c1 + 1.0f, 0.0f);
    }
  }
}

// ---------------- K4: merged segment-sum apply + FM + offloaded U/J (blocks B_SZ, B_SZ+1) ----------------
__global__ __launch_bounds__(512) void k_aggfm(
    const int* __restrict__ cnt, const int* __restrict__ scol,
    const float* __restrict__ sval, const float* __restrict__ rs,
    const float* __restrict__ fcw, const float* __restrict__ V,
    const float* __restrict__ Wt, const float* __restrict__ abae,
    float* __restrict__ uae, float* __restrict__ iae,
    float* __restrict__ linb, float* __restrict__ quadb,
    float* __restrict__ uj)
{
  __shared__ __align__(16) float ivec[2*D_DIM];
  __shared__ float redw[8];
  __shared__ float qpart[10];
  __shared__ float cninvS[A_DIM];
  const int b = blockIdx.x;
  const int tid = threadIdx.x, lane = tid & 63, wv = tid >> 6;

  if (b == B_SZ) {               // U_loss: Wt Gram (hidden under the 1024 agg blocks)
    if (tid < 400) {
      const int a = tid / 20, c = tid % 20;
      float dot = 0.f;
      #pragma unroll 4
      for (int d = 0; d < D_DIM; ++d) dot += Wt[d*A_DIM + a] * Wt[d*A_DIM + c];
      ivec[tid] = dot;
    }
    __syncthreads();
    if (tid < A_DIM) cninvS[tid] = 1.0f / fmaxf(sqrtf(ivec[tid*21]), EPS_);
    __syncthreads();
    float u = 0.f;
    if (tid < 400) {
      const int a = tid / 20, c = tid % 20;
      const float g = ivec[tid]*cninvS[a]*cninvS[c] - (a==c ? 1.0f : 0.0f);
      u = g*g;
    }
    #pragma unroll
    for (int o = 32; o > 0; o >>= 1) u += __shfl_xor(u, o);
    if (lane == 0) redw[wv] = u;
    __syncthreads();
    if (tid == 0) {
      float s = 0.f;
      #pragma unroll
      for (int i = 0; i < 8; ++i) s += redw[i];
      uj[0] = s;
    }
    return;
  }
  if (b == B_SZ + 1) {           // J: sum of abae
    float s = 0.f;
    for (int i = tid; i < RN_TOT; i += 512) s += abae[i];
    #pragma unroll
    for (int o = 32; o > 0; o >>= 1) s += __shfl_xor(s, o);
    if (lane == 0) redw[wv] = s;
    __syncthreads();
    if (tid == 0) {
      float t = 0.f;
      #pragma unroll
      for (int i = 0; i < 8; ++i) t += redw[i];
      uj[1] = t;
    }
    return;
  }

  if (tid < D_DIM) {
    int n = cnt[b]; n = n < SLOT_CAP ? n : SLOT_CAP;
    const int* cols = scol + (size_t)b*SLOT_CAP;
    const float* vals = sval + (size_t)b*SLOT_CAP;
    float acc = 0.f;
    for (int j = 0; j < n; ++j) acc += vals[j] * rs[(size_t)cols[j]*D_DIM + tid];
    ivec[tid] = acc;
    uae[(size_t)b*D_DIM + tid] = acc;
  } else if (tid >= 256 && tid < 256 + D_DIM) {
    const int t = tid - 256;
    int n = cnt[B_SZ + b]; n = n < SLOT_CAP ? n : SLOT_CAP;
    const int* cols = scol + (size_t)(B_SZ + b)*SLOT_CAP;
    const float* vals = sval + (size_t)(B_SZ + b)*SLOT_CAP;
    float acc = 0.f;
    for (int j = 0; j < n; ++j) acc += vals[j] * rs[(size_t)cols[j]*D_DIM + t];
    ivec[D_DIM + t] = acc;
    iae[(size_t)b*D_DIM + t] = acc;
  }
  __syncthreads();

  float lv = 0.f;
  if (tid < 2*D_DIM) lv = ivec[tid] * fcw[tid];
  #pragma unroll
  for (int o = 32; o > 0; o >>= 1) lv += __shfl_xor(lv, o);
  if (lane == 0) redw[wv] = lv;

  {
    const int k = wv;
    float s1 = 0.f, s2 = 0.f;
    for (int f = lane; f < 2*D_DIM; f += 64) {
      const float x = ivec[f];
      const float vk = V[f*10 + k];
      s1 += x*vk; s2 += x*x*vk*vk;
    }
    #pragma unroll
    for (int o = 32; o > 0; o >>= 1) { s1 += __shfl_xor(s1,o); s2 += __shfl_xor(s2,o); }
    if (lane == 0) qpart[k] = s1*s1 - s2;
  }
  if (wv < 2) {
    const int k = 8 + wv;
    float s1 = 0.f, s2 = 0.f;
    for (int f = lane; f < 2*D_DIM; f += 64) {
      const float x = ivec[f];
      const float vk = V[f*10 + k];
      s1 += x*vk; s2 += x*x*vk*vk;
    }
    #pragma unroll
    for (int o = 32; o > 0; o >>= 1) { s1 += __shfl_xor(s1,o); s2 += __shfl_xor(s2,o); }
    if (lane == 0) qpart[k] = s1*s1 - s2;
  }
  __syncthreads();
  if (tid == 0) {
    float lin = 0.f;
    #pragma unroll
    for (int i = 0; i < 8; ++i) lin += redw[i];
    float q = 0.f;
    #pragma unroll
    for (int i = 0; i < 10; ++i) q += qpart[i];
    linb[b] = lin; quadb[b] = q;
  }
}

// ---------------- K5: quad-reduce + prediction + final combine (U/J precomputed) ----------------
__global__ __launch_bounds__(1024) void k_final2(
    const float* __restrict__ quadb, const float* __restrict__ linb,
    const float* __restrict__ fcb, const int* __restrict__ user,
    const int* __restrict__ item, const float* __restrict__ busers,
    const float* __restrict__ bitems, const float* __restrict__ label,
    const float* __restrict__ uj,
    float* __restrict__ pred, float* __restrict__ rl, float* __restrict__ obj)
{
  __shared__ float sA[16], sC[16];
  __shared__ float quad_s;
  const int tid = threadIdx.x;
  const int lane = tid & 63;
  const int wv = tid >> 6;

  float q = quadb[tid];
  #pragma unroll
  for (int o = 32; o > 0; o >>= 1) q += __shfl_xor(q, o);
  if (lane == 0) sA[wv] = q;
  __syncthreads();
  if (wv == 0) {
    float s = (lane < 16) ? sA[lane] : 0.f;
    #pragma unroll
    for (int o = 32; o > 0; o >>= 1) s += __shfl_xor(s, o);
    if (lane == 0) quad_s = s;
  }
  __syncthreads();

  const float p = 0.5f*quad_s + linb[tid] + fcb[0]
                + busers[user[tid]] + bitems[item[tid]];
  pred[tid] = p;
  const float dd = p - label[tid];
  const float myrl = dd*dd;
  rl[tid] = myrl;

  float ms = myrl;
  #pragma unroll
  for (int o = 32; o > 0; o >>= 1) ms += __shfl_xor(ms, o);
  if (lane == 0) sC[wv] = ms;
  __syncthreads();
  if (tid == 0) {
    float Ms = 0.f;
    for (int i = 0; i < 16; ++i) Ms += sC[i];
    obj[0] = Ms/1024.0f + 0.01f*(uj[1]/8192.0f) + 0.01f*(uj[0]/400.0f);
  }
}

extern "C" void kernel_launch(void* const* d_in, const int* in_sizes, int n_in,
                              void* d_out, int out_size, void* d_ws, size_t ws_size,
                              hipStream_t stream) {
  const int*   hist   = (const int*)  d_in[0];
  const int*   neg    = (const int*)  d_in[1];
  const int*   user   = (const int*)  d_in[2];
  const int*   item   = (const int*)  d_in[3];
  const float* label  = (const float*)d_in[4];
  const int*   uidx   = (const int*)  d_in[5];
  const float* uval   = (const float*)d_in[6];
  const int*   iidx   = (const int*)  d_in[7];
  const float* ival   = (const float*)d_in[8];
  const float* emb    = (const float*)d_in[9];
  const float* Wm     = (const float*)d_in[10];
  const float* Ww     = (const float*)d_in[11];
  const float* bw     = (const float*)d_in[12];
  const float* Wt     = (const float*)d_in[13];
  const float* fcw    = (const float*)d_in[14];
  const float* fcb    = (const float*)d_in[15];
  const float* V      = (const float*)d_in[16];
  const float* busers = (const float*)d_in[17];
  const float* bitems = (const float*)d_in[18];

  float* out  = (float*)d_out;
  float* obj  = out;                       // 1
  float* rl   = out + 1;                   // 1024
  float* abae = out + 1 + B_SZ;            // 8192
  float* pred = out + 1 + B_SZ + RN_TOT;   // 1024
  float* uae  = pred + B_SZ;               // 204800
  float* iae  = uae + (size_t)B_SZ*D_DIM;  // 204800

  float* ws     = (float*)d_ws;
  float* rs     = ws;                              // R*D
  float* ys_all = rs + (size_t)R_TOT*D_DIM;        // R*D
  float* zn_all = ys_all + (size_t)R_TOT*D_DIM;    // RN*D
  float* vv_reg = zn_all + (size_t)RN_TOT*D_DIM;   // R*D region: vvh (fp16) + uj
  float* linb   = vv_reg + (size_t)R_TOT*D_DIM;    // B
  float* quadb  = linb + B_SZ;                     // B
  float* sval   = quadb + B_SZ;                    // 2*B*SLOT_CAP floats
  int*   scol   = (int*)(sval + (size_t)2*B_SZ*SLOT_CAP);   // 2*B*SLOT_CAP ints
  int*   cnt    = scol + (size_t)2*B_SZ*SLOT_CAP;           // 2*B ints
  ushort* emb_h = (ushort*)(cnt + 2*B_SZ);                  // VOCAB*D halves
  ushort* vvh   = (ushort*)vv_reg;                 // R*D halves (first half of region)
  float*  uj    = vv_reg + (size_t)R_TOT*D_DIM/2 + 16;      // past vvh, aligned slack

  const int cast_blocks = (VOCAB_C*D_DIM/4 + 255)/256;      // 6250

  k_cast       <<<cast_blocks, 256, 0, stream>>>(emb, emb_h, cnt);
  k_means_phase<<<S_TOT + NBUCK_BLK, 256, 0, stream>>>(hist, neg, emb_h,
                                                       ys_all, zn_all,
                                                       uidx, uval, iidx, ival,
                                                       cnt, scol, sval, 0, 0);
  k_means_phase<<<S_TOT, 256, 0, stream>>>(hist, neg, emb_h,
                                           ys_all, zn_all,
                                           uidx, uval, iidx, ival,
                                           cnt, scol, sval, VHALF, 1);
  k_matvec     <<<R_TOT/KB_RT, 256, 0, stream>>>(ys_all, Wm, vvh);
  k_attn       <<<R_TOT, 512, 0, stream>>>(hist, emb_h, vvh, Ww, bw, Wt,
                                           zn_all, rs, abae);
  k_aggfm      <<<B_SZ + 2, 512, 0, stream>>>(cnt, scol, sval, rs, fcw, V, Wt, abae,
                                              uae, iae, linb, quadb, uj);
  k_final2     <<<1, 1024, 0, stream>>>(quadb, linb, fcb, user, item, busers, bitems,
                                        label, uj, pred, rl, obj);
}